// Round 1
// baseline (1708.470 us; speedup 1.0000x reference)
//
#include <hip/hip_runtime.h>
#include <hip/hip_bf16.h>
#include <math.h>

#define H_DIM 1024
#define SEQ   2048
#define BATCH 2
#define NHEAD 16
#define DKV   64
#define ROWS  (BATCH*SEQ)   // 4096

typedef __attribute__((ext_vector_type(8))) short short8;
typedef __attribute__((ext_vector_type(4))) float f32x4;

static __device__ __forceinline__ unsigned short f32_bf16(float f) {
    unsigned int u = __builtin_bit_cast(unsigned int, f);
    u += 0x7FFF + ((u >> 16) & 1);          // RNE; inputs are well-behaved (no NaN)
    return (unsigned short)(u >> 16);
}

// ---------------- fp32 -> bf16 weight conversion ----------------
__global__ __launch_bounds__(256) void cvt_f32_bf16(const float* __restrict__ in,
                                                    unsigned short* __restrict__ out,
                                                    int n4) {
    int i = blockIdx.x * 256 + threadIdx.x;
    if (i >= n4) return;
    float4 v = ((const float4*)in)[i];
    ushort4 o;
    o.x = f32_bf16(v.x); o.y = f32_bf16(v.y);
    o.z = f32_bf16(v.z); o.w = f32_bf16(v.w);
    ((ushort4*)out)[i] = o;
}

// ---------------- LayerNorm (fp32 in -> bf16 out), one block per row ----------------
__global__ __launch_bounds__(256) void ln_bf16(const float* __restrict__ x,
                                               const float* __restrict__ w,
                                               const float* __restrict__ bb,
                                               unsigned short* __restrict__ out) {
    int row = blockIdx.x;
    int tid = threadIdx.x;
    float4 v = ((const float4*)(x + (size_t)row * H_DIM))[tid];
    float s  = v.x + v.y + v.z + v.w;
    float s2 = v.x*v.x + v.y*v.y + v.z*v.z + v.w*v.w;
    #pragma unroll
    for (int off = 1; off < 64; off <<= 1) {
        s  += __shfl_xor(s,  off, 64);
        s2 += __shfl_xor(s2, off, 64);
    }
    __shared__ float red[8];
    int wv = tid >> 6;
    if ((tid & 63) == 0) { red[wv] = s; red[4 + wv] = s2; }
    __syncthreads();
    s  = red[0] + red[1] + red[2] + red[3];
    s2 = red[4] + red[5] + red[6] + red[7];
    float mu = s * (1.0f / H_DIM);
    float rs = rsqrtf(s2 * (1.0f / H_DIM) - mu * mu + 1e-5f);
    float4 wv4 = ((const float4*)w)[tid];
    float4 bv4 = ((const float4*)bb)[tid];
    ushort4 o;
    o.x = f32_bf16((v.x - mu) * rs * wv4.x + bv4.x);
    o.y = f32_bf16((v.y - mu) * rs * wv4.y + bv4.y);
    o.z = f32_bf16((v.z - mu) * rs * wv4.z + bv4.z);
    o.w = f32_bf16((v.w - mu) * rs * wv4.w + bv4.w);
    ((ushort4*)(out + (size_t)row * H_DIM))[tid] = o;
}

// ---------------- bf16 MFMA GEMM, 64x64 block tile, 4 waves (2x2), epilogues ----------------
// EPI 0: outF = acc + bias            (fp32 store)
// EPI 1: outF = resid + acc + bias    (fp32 store)
// EPI 2: outH = bf16(gelu(acc+bias))  (bf16 store)
template<int EPI>
__global__ __launch_bounds__(256) void gemm64(const unsigned short* __restrict__ A,
                                              const unsigned short* __restrict__ B,
                                              const float* __restrict__ bias,
                                              const float* __restrict__ resid,
                                              float* __restrict__ outF,
                                              unsigned short* __restrict__ outH,
                                              int M, int N, int K) {
    __shared__ __attribute__((aligned(16))) unsigned short As[64][40];
    __shared__ __attribute__((aligned(16))) unsigned short Bs[32][72];
    int tid  = threadIdx.x;
    int wave = tid >> 6, lane = tid & 63;
    int wm = wave & 1, wn = wave >> 1;
    int m0 = blockIdx.y * 64, n0 = blockIdx.x * 64;
    int l15 = lane & 15, lk = lane >> 4;

    f32x4 acc[2][2] = {};

    int arow = tid >> 2, acg = (tid & 3) * 8;
    int brow = tid >> 3, bcg = (tid & 7) * 8;
    const unsigned short* aptr = A + (size_t)(m0 + arow) * K + acg;
    const unsigned short* bptr = B + (size_t)brow * N + n0 + bcg;

    for (int k0 = 0; k0 < K; k0 += 32) {
        __syncthreads();
        *(short8*)&As[arow][acg] = *(const short8*)aptr;  aptr += 32;
        *(short8*)&Bs[brow][bcg] = *(const short8*)bptr;  bptr += (size_t)32 * N;
        __syncthreads();

        short8 af[2];
        #pragma unroll
        for (int mi = 0; mi < 2; ++mi)
            af[mi] = *(const short8*)&As[wm * 32 + mi * 16 + l15][lk * 8];
        short8 bf[2];
        #pragma unroll
        for (int ni = 0; ni < 2; ++ni) {
            #pragma unroll
            for (int i = 0; i < 8; ++i)
                ((short*)&bf[ni])[i] = (short)Bs[lk * 8 + i][wn * 32 + ni * 16 + l15];
        }
        #pragma unroll
        for (int mi = 0; mi < 2; ++mi)
            #pragma unroll
            for (int ni = 0; ni < 2; ++ni)
                acc[mi][ni] = __builtin_amdgcn_mfma_f32_16x16x32_bf16(af[mi], bf[ni], acc[mi][ni], 0, 0, 0);
    }

    #pragma unroll
    for (int mi = 0; mi < 2; ++mi) {
        #pragma unroll
        for (int ni = 0; ni < 2; ++ni) {
            int col = n0 + wn * 32 + ni * 16 + l15;
            float bv = bias[col];
            #pragma unroll
            for (int j = 0; j < 4; ++j) {
                int row = m0 + wm * 32 + mi * 16 + lk * 4 + j;
                size_t idx = (size_t)row * N + col;
                float c = acc[mi][ni][j] + bv;
                if (EPI == 0) {
                    outF[idx] = c;
                } else if (EPI == 1) {
                    outF[idx] = resid[idx] + c;
                } else {
                    float g = 0.5f * c * (1.0f + erff(c * 0.70710678118f));
                    outH[idx] = f32_bf16(g);
                }
            }
        }
    }
}

// ---------------- causal flash attention (fp32 vector), 64-row q tile per block ----------------
__global__ __launch_bounds__(256) void attn_fwd(const float* __restrict__ qkv,
                                                unsigned short* __restrict__ out) {
    int qt = blockIdx.x, h = blockIdx.y, b = blockIdx.z;
    int tid = threadIdx.x;
    int wave = tid >> 6, lane = tid & 63;
    int rl = lane >> 2, grp = lane & 3;
    int row = wave * 16 + rl;        // 0..63 within q tile
    int qg  = qt * 64 + row;         // global q index

    __shared__ __attribute__((aligned(16))) float qs[64][68];
    __shared__ __attribute__((aligned(16))) float ks[64][68];
    __shared__ __attribute__((aligned(16))) float vs[64][68];

    for (int idx = tid; idx < 64 * 64; idx += 256) {
        int i = idx >> 6, d = idx & 63;
        qs[i][d] = qkv[(size_t)(b * SEQ + qt * 64 + i) * 3072 + h * DKV + d];
    }

    float m = -INFINITY, lsum = 0.0f;
    float acc[16];
    #pragma unroll
    for (int j = 0; j < 16; ++j) acc[j] = 0.0f;

    for (int kt = 0; kt <= qt; ++kt) {
        __syncthreads();
        for (int idx = tid; idx < 64 * 64; idx += 256) {
            int i = idx >> 6, d = idx & 63;
            const float* p = &qkv[(size_t)(b * SEQ + kt * 64 + i) * 3072 + h * DKV + d];
            ks[i][d] = p[H_DIM];        // K section
            vs[i][d] = p[2 * H_DIM];    // V section
        }
        __syncthreads();

        // scores for this thread: its q row x 16 k's (grp*16..+15)
        float sc[16];
        #pragma unroll
        for (int kk = 0; kk < 16; ++kk) sc[kk] = 0.0f;
        for (int d4 = 0; d4 < 16; ++d4) {
            float4 q4 = *(const float4*)&qs[row][d4 * 4];
            #pragma unroll
            for (int kk = 0; kk < 16; ++kk) {
                float4 k4 = *(const float4*)&ks[grp * 16 + kk][d4 * 4];
                sc[kk] += q4.x * k4.x + q4.y * k4.y + q4.z * k4.z + q4.w * k4.w;
            }
        }
        int kbase = kt * 64 + grp * 16;
        #pragma unroll
        for (int kk = 0; kk < 16; ++kk)
            sc[kk] = (kbase + kk <= qg) ? sc[kk] * 0.125f : -INFINITY;

        float mx = sc[0];
        #pragma unroll
        for (int kk = 1; kk < 16; ++kk) mx = fmaxf(mx, sc[kk]);
        mx = fmaxf(mx, __shfl_xor(mx, 1, 64));
        mx = fmaxf(mx, __shfl_xor(mx, 2, 64));
        float mn = fmaxf(m, mx);
        float scale = __expf(m - mn);   // m=-inf on first tile -> 0; mn always finite (diag valid)
        float p16[16]; float psum = 0.0f;
        #pragma unroll
        for (int kk = 0; kk < 16; ++kk) { p16[kk] = __expf(sc[kk] - mn); psum += p16[kk]; }
        psum += __shfl_xor(psum, 1, 64);
        psum += __shfl_xor(psum, 2, 64);
        lsum = lsum * scale + psum;
        m = mn;
        #pragma unroll
        for (int j = 0; j < 16; ++j) acc[j] *= scale;

        #pragma unroll
        for (int k = 0; k < 64; ++k) {
            float pk = __shfl(p16[k & 15], (lane & 60) | (k >> 4), 64);
            float4 v0 = *(const float4*)&vs[k][grp * 16 + 0];
            float4 v1 = *(const float4*)&vs[k][grp * 16 + 4];
            float4 v2 = *(const float4*)&vs[k][grp * 16 + 8];
            float4 v3 = *(const float4*)&vs[k][grp * 16 + 12];
            acc[0]  += pk * v0.x; acc[1]  += pk * v0.y; acc[2]  += pk * v0.z; acc[3]  += pk * v0.w;
            acc[4]  += pk * v1.x; acc[5]  += pk * v1.y; acc[6]  += pk * v1.z; acc[7]  += pk * v1.w;
            acc[8]  += pk * v2.x; acc[9]  += pk * v2.y; acc[10] += pk * v2.z; acc[11] += pk * v2.w;
            acc[12] += pk * v3.x; acc[13] += pk * v3.y; acc[14] += pk * v3.z; acc[15] += pk * v3.w;
        }
    }

    float inv = 1.0f / lsum;
    size_t ob = (size_t)(b * SEQ + qg) * H_DIM + h * DKV + grp * 16;
    #pragma unroll
    for (int j = 0; j < 16; ++j) out[ob + j] = f32_bf16(acc[j] * inv);
}

// ---------------- launch ----------------
extern "C" void kernel_launch(void* const* d_in, const int* in_sizes, int n_in,
                              void* d_out, int out_size, void* d_ws, size_t ws_size,
                              hipStream_t stream) {
    const float* x     = (const float*)d_in[0];
    const float* ln1w  = (const float*)d_in[1];
    const float* ln1b  = (const float*)d_in[2];
    const float* Wqkv  = (const float*)d_in[3];
    const float* bqkv  = (const float*)d_in[4];
    const float* Wo    = (const float*)d_in[5];
    const float* bo    = (const float*)d_in[6];
    const float* ln2w  = (const float*)d_in[7];
    const float* ln2b  = (const float*)d_in[8];
    const float* Wfc   = (const float*)d_in[9];
    const float* bfc   = (const float*)d_in[10];
    const float* Wproj = (const float*)d_in[11];
    const float* bproj = (const float*)d_in[12];
    float* out = (float*)d_out;

    char* ws = (char*)d_ws;
    size_t off = 0;
    auto take = [&](size_t bytes) {
        void* p = ws + off;
        off += (bytes + 255) & ~(size_t)255;
        return p;
    };

    unsigned short* Wq_h  = (unsigned short*)take((size_t)1024 * 3072 * 2);
    unsigned short* Wo_h  = (unsigned short*)take((size_t)1024 * 1024 * 2);
    unsigned short* Wfc_h = (unsigned short*)take((size_t)1024 * 4096 * 2);
    unsigned short* Wp_h  = (unsigned short*)take((size_t)4096 * 1024 * 2);
    unsigned short* xn1   = (unsigned short*)take((size_t)ROWS * 1024 * 2);
    float*          qkv   = (float*)take((size_t)ROWS * 3072 * 4);
    unsigned short* attn  = (unsigned short*)take((size_t)ROWS * 1024 * 2);
    float*          x1    = (float*)take((size_t)ROWS * 1024 * 4);
    unsigned short* xn2   = (unsigned short*)take((size_t)ROWS * 1024 * 2);
    unsigned short* hbuf  = (unsigned short*)take((size_t)ROWS * 4096 * 2);

    // weight conversions (every call; deterministic)
    cvt_f32_bf16<<<(1024 * 3072 / 4 + 255) / 256, 256, 0, stream>>>(Wqkv,  Wq_h,  1024 * 3072 / 4);
    cvt_f32_bf16<<<(1024 * 1024 / 4 + 255) / 256, 256, 0, stream>>>(Wo,    Wo_h,  1024 * 1024 / 4);
    cvt_f32_bf16<<<(1024 * 4096 / 4 + 255) / 256, 256, 0, stream>>>(Wfc,   Wfc_h, 1024 * 4096 / 4);
    cvt_f32_bf16<<<(4096 * 1024 / 4 + 255) / 256, 256, 0, stream>>>(Wproj, Wp_h,  4096 * 1024 / 4);

    // LN1 -> xn1 (bf16)
    ln_bf16<<<ROWS, 256, 0, stream>>>(x, ln1w, ln1b, xn1);

    // QKV = xn1 @ Wqkv + bqkv   (fp32 out)
    gemm64<0><<<dim3(3072 / 64, ROWS / 64), 256, 0, stream>>>(xn1, Wq_h, bqkv, nullptr, qkv, nullptr, ROWS, 3072, 1024);

    // causal attention -> attn (bf16)
    attn_fwd<<<dim3(SEQ / 64, NHEAD, BATCH), 256, 0, stream>>>(qkv, attn);

    // x1 = x + attn @ Wo + bo
    gemm64<1><<<dim3(1024 / 64, ROWS / 64), 256, 0, stream>>>(attn, Wo_h, bo, x, x1, nullptr, ROWS, 1024, 1024);

    // LN2 -> xn2 (bf16)
    ln_bf16<<<ROWS, 256, 0, stream>>>(x1, ln2w, ln2b, xn2);

    // h = gelu(xn2 @ Wfc + bfc) (bf16)
    gemm64<2><<<dim3(4096 / 64, ROWS / 64), 256, 0, stream>>>(xn2, Wfc_h, bfc, nullptr, nullptr, hbuf, ROWS, 4096, 1024);

    // out = x1 + h @ Wproj + bproj
    gemm64<1><<<dim3(1024 / 64, ROWS / 64), 256, 0, stream>>>(hbuf, Wp_h, bproj, x1, out, nullptr, ROWS, 1024, 4096);
}

// Round 2
// 514.934 us; speedup vs baseline: 3.3178x; 3.3178x over previous
//
#include <hip/hip_runtime.h>
#include <hip/hip_bf16.h>
#include <math.h>

#define H_DIM 1024
#define SEQ   2048
#define BATCH 2
#define NHEAD 16
#define DKV   64
#define ROWS  (BATCH*SEQ)   // 4096

typedef __attribute__((ext_vector_type(8))) short short8;
typedef __attribute__((ext_vector_type(4))) float f32x4;

static __device__ __forceinline__ unsigned short f32_bf16(float f) {
    unsigned int u = __builtin_bit_cast(unsigned int, f);
    u += 0x7FFF + ((u >> 16) & 1);          // RNE; inputs are well-behaved (no NaN)
    return (unsigned short)(u >> 16);
}

// ---------------- fp32 -> bf16 weight conversion ----------------
__global__ __launch_bounds__(256) void cvt_f32_bf16(const float* __restrict__ in,
                                                    unsigned short* __restrict__ out,
                                                    int n4) {
    int i = blockIdx.x * 256 + threadIdx.x;
    if (i >= n4) return;
    float4 v = ((const float4*)in)[i];
    ushort4 o;
    o.x = f32_bf16(v.x); o.y = f32_bf16(v.y);
    o.z = f32_bf16(v.z); o.w = f32_bf16(v.w);
    ((ushort4*)out)[i] = o;
}

// ---------------- LayerNorm (fp32 in -> bf16 out), one block per row ----------------
__global__ __launch_bounds__(256) void ln_bf16(const float* __restrict__ x,
                                               const float* __restrict__ w,
                                               const float* __restrict__ bb,
                                               unsigned short* __restrict__ out) {
    int row = blockIdx.x;
    int tid = threadIdx.x;
    float4 v = ((const float4*)(x + (size_t)row * H_DIM))[tid];
    float s  = v.x + v.y + v.z + v.w;
    float s2 = v.x*v.x + v.y*v.y + v.z*v.z + v.w*v.w;
    #pragma unroll
    for (int off = 1; off < 64; off <<= 1) {
        s  += __shfl_xor(s,  off, 64);
        s2 += __shfl_xor(s2, off, 64);
    }
    __shared__ float red[8];
    int wv = tid >> 6;
    if ((tid & 63) == 0) { red[wv] = s; red[4 + wv] = s2; }
    __syncthreads();
    s  = red[0] + red[1] + red[2] + red[3];
    s2 = red[4] + red[5] + red[6] + red[7];
    float mu = s * (1.0f / H_DIM);
    float rs = rsqrtf(s2 * (1.0f / H_DIM) - mu * mu + 1e-5f);
    float4 wv4 = ((const float4*)w)[tid];
    float4 bv4 = ((const float4*)bb)[tid];
    ushort4 o;
    o.x = f32_bf16((v.x - mu) * rs * wv4.x + bv4.x);
    o.y = f32_bf16((v.y - mu) * rs * wv4.y + bv4.y);
    o.z = f32_bf16((v.z - mu) * rs * wv4.z + bv4.z);
    o.w = f32_bf16((v.w - mu) * rs * wv4.w + bv4.w);
    ((ushort4*)(out + (size_t)row * H_DIM))[tid] = o;
}

// ---------------- bf16 MFMA GEMM, 64x64 block tile, 4 waves (2x2), epilogues ----------------
// EPI 0: outF = acc + bias            (fp32 store)
// EPI 1: outF = resid + acc + bias    (fp32 store)
// EPI 2: outH = bf16(gelu(acc+bias))  (bf16 store)
// EPI 3: outH = bf16(acc+bias)        (bf16 store)
template<int EPI>
__global__ __launch_bounds__(256) void gemm64(const unsigned short* __restrict__ A,
                                              const unsigned short* __restrict__ B,
                                              const float* __restrict__ bias,
                                              const float* __restrict__ resid,
                                              float* __restrict__ outF,
                                              unsigned short* __restrict__ outH,
                                              int M, int N, int K) {
    __shared__ __attribute__((aligned(16))) unsigned short As[64][40];
    __shared__ __attribute__((aligned(16))) unsigned short Bs[32][72];
    int tid  = threadIdx.x;
    int wave = tid >> 6, lane = tid & 63;
    int wm = wave & 1, wn = wave >> 1;
    int m0 = blockIdx.y * 64, n0 = blockIdx.x * 64;
    int l15 = lane & 15, lk = lane >> 4;

    f32x4 acc[2][2] = {};

    int arow = tid >> 2, acg = (tid & 3) * 8;
    int brow = tid >> 3, bcg = (tid & 7) * 8;
    const unsigned short* aptr = A + (size_t)(m0 + arow) * K + acg;
    const unsigned short* bptr = B + (size_t)brow * N + n0 + bcg;

    for (int k0 = 0; k0 < K; k0 += 32) {
        __syncthreads();
        *(short8*)&As[arow][acg] = *(const short8*)aptr;  aptr += 32;
        *(short8*)&Bs[brow][bcg] = *(const short8*)bptr;  bptr += (size_t)32 * N;
        __syncthreads();

        short8 af[2];
        #pragma unroll
        for (int mi = 0; mi < 2; ++mi)
            af[mi] = *(const short8*)&As[wm * 32 + mi * 16 + l15][lk * 8];
        short8 bf[2];
        #pragma unroll
        for (int ni = 0; ni < 2; ++ni) {
            #pragma unroll
            for (int i = 0; i < 8; ++i)
                ((short*)&bf[ni])[i] = (short)Bs[lk * 8 + i][wn * 32 + ni * 16 + l15];
        }
        #pragma unroll
        for (int mi = 0; mi < 2; ++mi)
            #pragma unroll
            for (int ni = 0; ni < 2; ++ni)
                acc[mi][ni] = __builtin_amdgcn_mfma_f32_16x16x32_bf16(af[mi], bf[ni], acc[mi][ni], 0, 0, 0);
    }

    #pragma unroll
    for (int mi = 0; mi < 2; ++mi) {
        #pragma unroll
        for (int ni = 0; ni < 2; ++ni) {
            int col = n0 + wn * 32 + ni * 16 + l15;
            float bv = bias[col];
            #pragma unroll
            for (int j = 0; j < 4; ++j) {
                int row = m0 + wm * 32 + mi * 16 + lk * 4 + j;
                size_t idx = (size_t)row * N + col;
                float c = acc[mi][ni][j] + bv;
                if (EPI == 0) {
                    outF[idx] = c;
                } else if (EPI == 1) {
                    outF[idx] = resid[idx] + c;
                } else if (EPI == 2) {
                    float g = 0.5f * c * (1.0f + erff(c * 0.70710678118f));
                    outH[idx] = f32_bf16(g);
                } else {
                    outH[idx] = f32_bf16(c);
                }
            }
        }
    }
}

// ---------------- causal flash attention, MFMA 16x16x32 bf16 ----------------
// One block per (b, h, 64-row q tile); 4 waves, wave w owns q rows w*16..w*16+15.
// qkv is bf16 [ROWS][3072] (Q | K | V sections).
__global__ __launch_bounds__(256) void attn_mfma(const unsigned short* __restrict__ qkv,
                                                 unsigned short* __restrict__ out) {
    int qt = gridDim.x - 1 - blockIdx.x;   // long blocks first (load balance)
    int h = blockIdx.y, b = blockIdx.z;
    int tid = threadIdx.x;
    int w = tid >> 6, l = tid & 63;
    int l15 = l & 15, lg = l >> 4;

    __shared__ __attribute__((aligned(16))) unsigned short Ks[64][72];
    __shared__ __attribute__((aligned(16))) unsigned short Vt[64][72];  // Vt[d][k]
    __shared__ __attribute__((aligned(16))) unsigned short Ps[4][16][72];

    // Q fragments: A-layout lane l holds Q[q=l15][d = dstep*32 + lg*8 + 0..7]
    short8 qf[2];
    {
        int qrow = qt * 64 + w * 16 + l15;
        const unsigned short* qp = qkv + (size_t)(b * SEQ + qrow) * 3072 + h * DKV + lg * 8;
        qf[0] = *(const short8*)qp;
        qf[1] = *(const short8*)(qp + 32);
    }

    float m[4], lsum[4];
    f32x4 oacc[4] = {};   // [dsub]; lane holds out[q=lg*4+j][d=dsub*16+l15]
    #pragma unroll
    for (int j = 0; j < 4; ++j) { m[j] = -1e30f; lsum[j] = 0.0f; }

    for (int kt = 0; kt <= qt; ++kt) {
        __syncthreads();   // previous tile's Ks/Vt reads complete
        // stage K rows: wave w stages rows w*16..w*16+15
        {
            int row = w * 16 + (l >> 2);
            int dg = (l & 3) * 16;
            const unsigned short* kp = qkv + (size_t)(b * SEQ + kt * 64 + row) * 3072 + H_DIM + h * DKV + dg;
            *(short8*)&Ks[row][dg]     = *(const short8*)kp;
            *(short8*)&Ks[row][dg + 8] = *(const short8*)(kp + 8);
        }
        // stage V transposed: wave w stages d-rows w*16..w*16+15; lane l = k index
        {
            const unsigned short* vp = qkv + (size_t)(b * SEQ + kt * 64 + l) * 3072 + 2 * H_DIM + h * DKV + w * 16;
            short8 v0 = *(const short8*)vp;
            short8 v1 = *(const short8*)(vp + 8);
            #pragma unroll
            for (int i = 0; i < 8; ++i) {
                Vt[w * 16 + i][l]     = (unsigned short)v0[i];
                Vt[w * 16 + 8 + i][l] = (unsigned short)v1[i];
            }
        }
        __syncthreads();

        // QK^T: sc[st] = Q(16xD) @ K^T(Dx16), st = k sub-tile
        f32x4 sc[4] = {};
        #pragma unroll
        for (int dstep = 0; dstep < 2; ++dstep) {
            #pragma unroll
            for (int st = 0; st < 4; ++st) {
                short8 kf = *(const short8*)&Ks[st * 16 + l15][dstep * 32 + lg * 8];
                sc[st] = __builtin_amdgcn_mfma_f32_16x16x32_bf16(qf[dstep], kf, sc[st], 0, 0, 0);
            }
        }

        // mask + online softmax (C layout: row=q=lg*4+j, col=k=l15)
        int qglob = qt * 64 + w * 16 + lg * 4;      // + j
        int kcol  = kt * 64 + l15;                  // + st*16
        bool diag = (kt == qt);
        float pv[4][4];                              // [st][j]
        float scale[4];
        #pragma unroll
        for (int j = 0; j < 4; ++j) {
            float mx = -1e30f;
            #pragma unroll
            for (int st = 0; st < 4; ++st) {
                float s = sc[st][j] * 0.125f;
                if (diag && (kcol + st * 16 > qglob + j)) s = -1e30f;
                pv[st][j] = s;
                mx = fmaxf(mx, s);
            }
            mx = fmaxf(mx, __shfl_xor(mx, 1, 64));
            mx = fmaxf(mx, __shfl_xor(mx, 2, 64));
            mx = fmaxf(mx, __shfl_xor(mx, 4, 64));
            mx = fmaxf(mx, __shfl_xor(mx, 8, 64));
            float mn = fmaxf(m[j], mx);
            scale[j] = __expf(m[j] - mn);
            float ps = 0.0f;
            #pragma unroll
            for (int st = 0; st < 4; ++st) {
                float p = __expf(pv[st][j] - mn);
                pv[st][j] = p;
                ps += p;
            }
            ps += __shfl_xor(ps, 1, 64);
            ps += __shfl_xor(ps, 2, 64);
            ps += __shfl_xor(ps, 4, 64);
            ps += __shfl_xor(ps, 8, 64);
            lsum[j] = lsum[j] * scale[j] + ps;
            m[j] = mn;
        }

        // P -> LDS (re-layout to A-fragment), per-wave region, no barrier needed
        #pragma unroll
        for (int st = 0; st < 4; ++st)
            #pragma unroll
            for (int j = 0; j < 4; ++j)
                Ps[w][lg * 4 + j][st * 16 + l15] = f32_bf16(pv[st][j]);

        // rescale O
        #pragma unroll
        for (int d = 0; d < 4; ++d)
            #pragma unroll
            for (int j = 0; j < 4; ++j)
                oacc[d][j] *= scale[j];

        // PV: O += P(16x64) @ V(64x64)
        #pragma unroll
        for (int ks = 0; ks < 2; ++ks) {
            short8 pf = *(const short8*)&Ps[w][l15][ks * 32 + lg * 8];
            #pragma unroll
            for (int d = 0; d < 4; ++d) {
                short8 vf = *(const short8*)&Vt[d * 16 + l15][ks * 32 + lg * 8];
                oacc[d] = __builtin_amdgcn_mfma_f32_16x16x32_bf16(pf, vf, oacc[d], 0, 0, 0);
            }
        }
    }

    // epilogue: normalize, store bf16
    #pragma unroll
    for (int j = 0; j < 4; ++j) {
        float inv = 1.0f / lsum[j];
        int qrow = qt * 64 + w * 16 + lg * 4 + j;
        size_t ob = (size_t)(b * SEQ + qrow) * H_DIM + h * DKV;
        #pragma unroll
        for (int d = 0; d < 4; ++d)
            out[ob + d * 16 + l15] = f32_bf16(oacc[d][j] * inv);
    }
}

// ---------------- launch ----------------
extern "C" void kernel_launch(void* const* d_in, const int* in_sizes, int n_in,
                              void* d_out, int out_size, void* d_ws, size_t ws_size,
                              hipStream_t stream) {
    const float* x     = (const float*)d_in[0];
    const float* ln1w  = (const float*)d_in[1];
    const float* ln1b  = (const float*)d_in[2];
    const float* Wqkv  = (const float*)d_in[3];
    const float* bqkv  = (const float*)d_in[4];
    const float* Wo    = (const float*)d_in[5];
    const float* bo    = (const float*)d_in[6];
    const float* ln2w  = (const float*)d_in[7];
    const float* ln2b  = (const float*)d_in[8];
    const float* Wfc   = (const float*)d_in[9];
    const float* bfc   = (const float*)d_in[10];
    const float* Wproj = (const float*)d_in[11];
    const float* bproj = (const float*)d_in[12];
    float* out = (float*)d_out;

    char* ws = (char*)d_ws;
    size_t off = 0;
    auto take = [&](size_t bytes) {
        void* p = ws + off;
        off += (bytes + 255) & ~(size_t)255;
        return p;
    };

    unsigned short* Wq_h  = (unsigned short*)take((size_t)1024 * 3072 * 2);
    unsigned short* Wo_h  = (unsigned short*)take((size_t)1024 * 1024 * 2);
    unsigned short* Wfc_h = (unsigned short*)take((size_t)1024 * 4096 * 2);
    unsigned short* Wp_h  = (unsigned short*)take((size_t)4096 * 1024 * 2);
    unsigned short* xn1   = (unsigned short*)take((size_t)ROWS * 1024 * 2);
    unsigned short* qkv_h = (unsigned short*)take((size_t)ROWS * 3072 * 2);
    unsigned short* attn  = (unsigned short*)take((size_t)ROWS * 1024 * 2);
    float*          x1    = (float*)take((size_t)ROWS * 1024 * 4);
    unsigned short* xn2   = (unsigned short*)take((size_t)ROWS * 1024 * 2);
    unsigned short* hbuf  = (unsigned short*)take((size_t)ROWS * 4096 * 2);

    // weight conversions (every call; deterministic)
    cvt_f32_bf16<<<(1024 * 3072 / 4 + 255) / 256, 256, 0, stream>>>(Wqkv,  Wq_h,  1024 * 3072 / 4);
    cvt_f32_bf16<<<(1024 * 1024 / 4 + 255) / 256, 256, 0, stream>>>(Wo,    Wo_h,  1024 * 1024 / 4);
    cvt_f32_bf16<<<(1024 * 4096 / 4 + 255) / 256, 256, 0, stream>>>(Wfc,   Wfc_h, 1024 * 4096 / 4);
    cvt_f32_bf16<<<(4096 * 1024 / 4 + 255) / 256, 256, 0, stream>>>(Wproj, Wp_h,  4096 * 1024 / 4);

    // LN1 -> xn1 (bf16)
    ln_bf16<<<ROWS, 256, 0, stream>>>(x, ln1w, ln1b, xn1);

    // QKV = xn1 @ Wqkv + bqkv   (bf16 out)
    gemm64<3><<<dim3(3072 / 64, ROWS / 64), 256, 0, stream>>>(xn1, Wq_h, bqkv, nullptr, nullptr, qkv_h, ROWS, 3072, 1024);

    // causal attention -> attn (bf16)
    attn_mfma<<<dim3(SEQ / 64, NHEAD, BATCH), 256, 0, stream>>>(qkv_h, attn);

    // x1 = x + attn @ Wo + bo
    gemm64<1><<<dim3(1024 / 64, ROWS / 64), 256, 0, stream>>>(attn, Wo_h, bo, x, x1, nullptr, ROWS, 1024, 1024);

    // LN2 -> xn2 (bf16)
    ln_bf16<<<ROWS, 256, 0, stream>>>(x1, ln2w, ln2b, xn2);

    // h = gelu(xn2 @ Wfc + bfc) (bf16)
    gemm64<2><<<dim3(4096 / 64, ROWS / 64), 256, 0, stream>>>(xn2, Wfc_h, bfc, nullptr, nullptr, hbuf, ROWS, 4096, 1024);

    // out = x1 + h @ Wproj + bproj
    gemm64<1><<<dim3(1024 / 64, ROWS / 64), 256, 0, stream>>>(hbuf, Wp_h, bproj, x1, out, nullptr, ROWS, 1024, 4096);
}

// Round 3
// 388.935 us; speedup vs baseline: 4.3927x; 1.3240x over previous
//
#include <hip/hip_runtime.h>
#include <hip/hip_bf16.h>
#include <math.h>

#define H_DIM 1024
#define SEQ   2048
#define BATCH 2
#define NHEAD 16
#define DKV   64
#define ROWS  (BATCH*SEQ)   // 4096

typedef __attribute__((ext_vector_type(8))) short short8;
typedef __attribute__((ext_vector_type(4))) float f32x4;

static __device__ __forceinline__ unsigned short f32_bf16(float f) {
    unsigned int u = __builtin_bit_cast(unsigned int, f);
    u += 0x7FFF + ((u >> 16) & 1);          // RNE
    return (unsigned short)(u >> 16);
}

static __device__ __forceinline__ void gload16(const unsigned short* g, unsigned short* l) {
    __builtin_amdgcn_global_load_lds(
        (const __attribute__((address_space(1))) void*)g,
        (__attribute__((address_space(3))) void*)l,
        16, 0, 0);
}

// ---------------- fp32 [K][N] -> bf16 [N][K] transpose ----------------
__global__ __launch_bounds__(256) void transpose_bf16(const float* __restrict__ in,
                                                      unsigned short* __restrict__ out,
                                                      int K, int N) {
    __shared__ float tile[32][33];
    int n0 = blockIdx.x * 32, k0 = blockIdx.y * 32;
    int tx = threadIdx.x & 31, ty = threadIdx.x >> 5;   // 32 x 8
    #pragma unroll
    for (int i = 0; i < 4; ++i)
        tile[ty + i * 8][tx] = in[(size_t)(k0 + ty + i * 8) * N + n0 + tx];
    __syncthreads();
    #pragma unroll
    for (int i = 0; i < 4; ++i)
        out[(size_t)(n0 + ty + i * 8) * K + k0 + tx] = f32_bf16(tile[tx][ty + i * 8]);
}

// ---------------- LayerNorm (fp32 in -> bf16 out), one block per row ----------------
__global__ __launch_bounds__(256) void ln_bf16(const float* __restrict__ x,
                                               const float* __restrict__ w,
                                               const float* __restrict__ bb,
                                               unsigned short* __restrict__ out) {
    int row = blockIdx.x;
    int tid = threadIdx.x;
    float4 v = ((const float4*)(x + (size_t)row * H_DIM))[tid];
    float s  = v.x + v.y + v.z + v.w;
    float s2 = v.x*v.x + v.y*v.y + v.z*v.z + v.w*v.w;
    #pragma unroll
    for (int off = 1; off < 64; off <<= 1) {
        s  += __shfl_xor(s,  off, 64);
        s2 += __shfl_xor(s2, off, 64);
    }
    __shared__ float red[8];
    int wv = tid >> 6;
    if ((tid & 63) == 0) { red[wv] = s; red[4 + wv] = s2; }
    __syncthreads();
    s  = red[0] + red[1] + red[2] + red[3];
    s2 = red[4] + red[5] + red[6] + red[7];
    float mu = s * (1.0f / H_DIM);
    float rs = rsqrtf(s2 * (1.0f / H_DIM) - mu * mu + 1e-5f);
    float4 wv4 = ((const float4*)w)[tid];
    float4 bv4 = ((const float4*)bb)[tid];
    ushort4 o;
    o.x = f32_bf16((v.x - mu) * rs * wv4.x + bv4.x);
    o.y = f32_bf16((v.y - mu) * rs * wv4.y + bv4.y);
    o.z = f32_bf16((v.z - mu) * rs * wv4.z + bv4.z);
    o.w = f32_bf16((v.w - mu) * rs * wv4.w + bv4.w);
    ((ushort4*)(out + (size_t)row * H_DIM))[tid] = o;
}

// ---------------- bf16 MFMA GEMM, 128x128 tile, global_load_lds staging ----------------
// A [M][K] bf16 row-major, Bt [N][K] bf16 row-major (pre-transposed weights).
// 4 waves in 2x2; each wave owns 64x64 (4x4 16x16 fragments). BK=32.
// EPI 0: outF = acc + bias            (fp32 store)
// EPI 1: outF = resid + acc + bias    (fp32 store)
// EPI 2: outH = bf16(gelu(acc+bias))  (bf16 store)
// EPI 3: outH = bf16(acc+bias)        (bf16 store)
template<int EPI>
__global__ __launch_bounds__(256) void gemm128(const unsigned short* __restrict__ A,
                                               const unsigned short* __restrict__ Bt,
                                               const float* __restrict__ bias,
                                               const float* __restrict__ resid,
                                               float* __restrict__ outF,
                                               unsigned short* __restrict__ outH,
                                               int N, int K) {
    __shared__ __attribute__((aligned(16))) unsigned short As[128][32];
    __shared__ __attribute__((aligned(16))) unsigned short Bs[128][32];
    int tid = threadIdx.x;
    int w = tid >> 6, l = tid & 63;
    int l15 = l & 15, lg = l >> 4;
    int wm = w & 1, wn = w >> 1;
    int m0 = blockIdx.y * 128, n0 = blockIdx.x * 128;

    f32x4 acc[4][4] = {};

    // staging: instruction j in {0,1}: 16B chunk index = (w*2+j)*64 + lane
    // row = idx>>2, colElem = (idx&3)*8 ; LDS dest = linear base + lane*16 (HW)
    int idx0 = (w * 2 + 0) * 64 + l;
    int idx1 = (w * 2 + 1) * 64 + l;
    const unsigned short* a0 = A  + (size_t)(m0 + (idx0 >> 2)) * K + (idx0 & 3) * 8;
    const unsigned short* a1 = A  + (size_t)(m0 + (idx1 >> 2)) * K + (idx1 & 3) * 8;
    const unsigned short* b0 = Bt + (size_t)(n0 + (idx0 >> 2)) * K + (idx0 & 3) * 8;
    const unsigned short* b1 = Bt + (size_t)(n0 + (idx1 >> 2)) * K + (idx1 & 3) * 8;
    unsigned short* lA0 = &As[0][0] + (w * 2 + 0) * 512;
    unsigned short* lA1 = &As[0][0] + (w * 2 + 1) * 512;
    unsigned short* lB0 = &Bs[0][0] + (w * 2 + 0) * 512;
    unsigned short* lB1 = &Bs[0][0] + (w * 2 + 1) * 512;

    for (int k0 = 0; k0 < K; k0 += 32) {
        __syncthreads();                    // prior ds_reads done before overwrite
        gload16(a0 + k0, lA0);
        gload16(a1 + k0, lA1);
        gload16(b0 + k0, lB0);
        gload16(b1 + k0, lB1);
        __syncthreads();                    // drains vmcnt(0): tiles resident

        short8 af[4], bf[4];
        #pragma unroll
        for (int mi = 0; mi < 4; ++mi)
            af[mi] = *(const short8*)&As[wm * 64 + mi * 16 + l15][lg * 8];
        #pragma unroll
        for (int ni = 0; ni < 4; ++ni)
            bf[ni] = *(const short8*)&Bs[wn * 64 + ni * 16 + l15][lg * 8];
        #pragma unroll
        for (int mi = 0; mi < 4; ++mi)
            #pragma unroll
            for (int ni = 0; ni < 4; ++ni)
                acc[mi][ni] = __builtin_amdgcn_mfma_f32_16x16x32_bf16(af[mi], bf[ni], acc[mi][ni], 0, 0, 0);
    }

    #pragma unroll
    for (int mi = 0; mi < 4; ++mi) {
        #pragma unroll
        for (int ni = 0; ni < 4; ++ni) {
            int col = n0 + wn * 64 + ni * 16 + l15;
            float bv = bias[col];
            #pragma unroll
            for (int j = 0; j < 4; ++j) {
                int row = m0 + wm * 64 + mi * 16 + lg * 4 + j;
                size_t idx = (size_t)row * N + col;
                float c = acc[mi][ni][j] + bv;
                if (EPI == 0) {
                    outF[idx] = c;
                } else if (EPI == 1) {
                    outF[idx] = resid[idx] + c;
                } else if (EPI == 2) {
                    float g = 0.5f * c * (1.0f + erff(c * 0.70710678118f));
                    outH[idx] = f32_bf16(g);
                } else {
                    outH[idx] = f32_bf16(c);
                }
            }
        }
    }
}

// ---------------- causal flash attention, MFMA 16x16x32 bf16 ----------------
__global__ __launch_bounds__(256) void attn_mfma(const unsigned short* __restrict__ qkv,
                                                 unsigned short* __restrict__ out) {
    int qt = gridDim.x - 1 - blockIdx.x;   // long blocks first (load balance)
    int h = blockIdx.y, b = blockIdx.z;
    int tid = threadIdx.x;
    int w = tid >> 6, l = tid & 63;
    int l15 = l & 15, lg = l >> 4;

    __shared__ __attribute__((aligned(16))) unsigned short Ks[64][72];
    __shared__ __attribute__((aligned(16))) unsigned short Vt[64][72];  // Vt[d][k]
    __shared__ __attribute__((aligned(16))) unsigned short Ps[4][16][72];

    short8 qf[2];
    {
        int qrow = qt * 64 + w * 16 + l15;
        const unsigned short* qp = qkv + (size_t)(b * SEQ + qrow) * 3072 + h * DKV + lg * 8;
        qf[0] = *(const short8*)qp;
        qf[1] = *(const short8*)(qp + 32);
    }

    float m[4], lsum[4];
    f32x4 oacc[4] = {};
    #pragma unroll
    for (int j = 0; j < 4; ++j) { m[j] = -1e30f; lsum[j] = 0.0f; }

    for (int kt = 0; kt <= qt; ++kt) {
        __syncthreads();
        {
            int row = w * 16 + (l >> 2);
            int dg = (l & 3) * 16;
            const unsigned short* kp = qkv + (size_t)(b * SEQ + kt * 64 + row) * 3072 + H_DIM + h * DKV + dg;
            *(short8*)&Ks[row][dg]     = *(const short8*)kp;
            *(short8*)&Ks[row][dg + 8] = *(const short8*)(kp + 8);
        }
        {
            const unsigned short* vp = qkv + (size_t)(b * SEQ + kt * 64 + l) * 3072 + 2 * H_DIM + h * DKV + w * 16;
            short8 v0 = *(const short8*)vp;
            short8 v1 = *(const short8*)(vp + 8);
            #pragma unroll
            for (int i = 0; i < 8; ++i) {
                Vt[w * 16 + i][l]     = (unsigned short)v0[i];
                Vt[w * 16 + 8 + i][l] = (unsigned short)v1[i];
            }
        }
        __syncthreads();

        f32x4 sc[4] = {};
        #pragma unroll
        for (int dstep = 0; dstep < 2; ++dstep) {
            #pragma unroll
            for (int st = 0; st < 4; ++st) {
                short8 kf = *(const short8*)&Ks[st * 16 + l15][dstep * 32 + lg * 8];
                sc[st] = __builtin_amdgcn_mfma_f32_16x16x32_bf16(qf[dstep], kf, sc[st], 0, 0, 0);
            }
        }

        int qglob = qt * 64 + w * 16 + lg * 4;
        int kcol  = kt * 64 + l15;
        bool diag = (kt == qt);
        float pv[4][4];
        float scale[4];
        #pragma unroll
        for (int j = 0; j < 4; ++j) {
            float mx = -1e30f;
            #pragma unroll
            for (int st = 0; st < 4; ++st) {
                float s = sc[st][j] * 0.125f;
                if (diag && (kcol + st * 16 > qglob + j)) s = -1e30f;
                pv[st][j] = s;
                mx = fmaxf(mx, s);
            }
            mx = fmaxf(mx, __shfl_xor(mx, 1, 64));
            mx = fmaxf(mx, __shfl_xor(mx, 2, 64));
            mx = fmaxf(mx, __shfl_xor(mx, 4, 64));
            mx = fmaxf(mx, __shfl_xor(mx, 8, 64));
            float mn = fmaxf(m[j], mx);
            scale[j] = __expf(m[j] - mn);
            float ps = 0.0f;
            #pragma unroll
            for (int st = 0; st < 4; ++st) {
                float p = __expf(pv[st][j] - mn);
                pv[st][j] = p;
                ps += p;
            }
            ps += __shfl_xor(ps, 1, 64);
            ps += __shfl_xor(ps, 2, 64);
            ps += __shfl_xor(ps, 4, 64);
            ps += __shfl_xor(ps, 8, 64);
            lsum[j] = lsum[j] * scale[j] + ps;
            m[j] = mn;
        }

        #pragma unroll
        for (int st = 0; st < 4; ++st)
            #pragma unroll
            for (int j = 0; j < 4; ++j)
                Ps[w][lg * 4 + j][st * 16 + l15] = f32_bf16(pv[st][j]);

        #pragma unroll
        for (int d = 0; d < 4; ++d)
            #pragma unroll
            for (int j = 0; j < 4; ++j)
                oacc[d][j] *= scale[j];

        #pragma unroll
        for (int ks = 0; ks < 2; ++ks) {
            short8 pf = *(const short8*)&Ps[w][l15][ks * 32 + lg * 8];
            #pragma unroll
            for (int d = 0; d < 4; ++d) {
                short8 vf = *(const short8*)&Vt[d * 16 + l15][ks * 32 + lg * 8];
                oacc[d] = __builtin_amdgcn_mfma_f32_16x16x32_bf16(pf, vf, oacc[d], 0, 0, 0);
            }
        }
    }

    #pragma unroll
    for (int j = 0; j < 4; ++j) {
        float inv = 1.0f / lsum[j];
        int qrow = qt * 64 + w * 16 + lg * 4 + j;
        size_t ob = (size_t)(b * SEQ + qrow) * H_DIM + h * DKV;
        #pragma unroll
        for (int d = 0; d < 4; ++d)
            out[ob + d * 16 + l15] = f32_bf16(oacc[d][j] * inv);
    }
}

// ---------------- launch ----------------
extern "C" void kernel_launch(void* const* d_in, const int* in_sizes, int n_in,
                              void* d_out, int out_size, void* d_ws, size_t ws_size,
                              hipStream_t stream) {
    const float* x     = (const float*)d_in[0];
    const float* ln1w  = (const float*)d_in[1];
    const float* ln1b  = (const float*)d_in[2];
    const float* Wqkv  = (const float*)d_in[3];
    const float* bqkv  = (const float*)d_in[4];
    const float* Wo    = (const float*)d_in[5];
    const float* bo    = (const float*)d_in[6];
    const float* ln2w  = (const float*)d_in[7];
    const float* ln2b  = (const float*)d_in[8];
    const float* Wfc   = (const float*)d_in[9];
    const float* bfc   = (const float*)d_in[10];
    const float* Wproj = (const float*)d_in[11];
    const float* bproj = (const float*)d_in[12];
    float* out = (float*)d_out;

    char* ws = (char*)d_ws;
    size_t off = 0;
    auto take = [&](size_t bytes) {
        void* p = ws + off;
        off += (bytes + 255) & ~(size_t)255;
        return p;
    };

    unsigned short* WqT  = (unsigned short*)take((size_t)3072 * 1024 * 2);  // [3072][1024]
    unsigned short* WoT  = (unsigned short*)take((size_t)1024 * 1024 * 2);  // [1024][1024]
    unsigned short* WfcT = (unsigned short*)take((size_t)4096 * 1024 * 2);  // [4096][1024]
    unsigned short* WpT  = (unsigned short*)take((size_t)1024 * 4096 * 2);  // [1024][4096]
    unsigned short* xn1   = (unsigned short*)take((size_t)ROWS * 1024 * 2);
    unsigned short* qkv_h = (unsigned short*)take((size_t)ROWS * 3072 * 2);
    unsigned short* attn  = (unsigned short*)take((size_t)ROWS * 1024 * 2);
    float*          x1    = (float*)take((size_t)ROWS * 1024 * 4);
    unsigned short* xn2   = (unsigned short*)take((size_t)ROWS * 1024 * 2);
    unsigned short* hbuf  = (unsigned short*)take((size_t)ROWS * 4096 * 2);

    // weight transposes fp32[K][N] -> bf16[N][K]
    transpose_bf16<<<dim3(3072 / 32, 1024 / 32), 256, 0, stream>>>(Wqkv,  WqT,  1024, 3072);
    transpose_bf16<<<dim3(1024 / 32, 1024 / 32), 256, 0, stream>>>(Wo,    WoT,  1024, 1024);
    transpose_bf16<<<dim3(4096 / 32, 1024 / 32), 256, 0, stream>>>(Wfc,   WfcT, 1024, 4096);
    transpose_bf16<<<dim3(1024 / 32, 4096 / 32), 256, 0, stream>>>(Wproj, WpT,  4096, 1024);

    // LN1 -> xn1 (bf16)
    ln_bf16<<<ROWS, 256, 0, stream>>>(x, ln1w, ln1b, xn1);

    // QKV = xn1 @ Wqkv + bqkv   (bf16 out)
    gemm128<3><<<dim3(3072 / 128, ROWS / 128), 256, 0, stream>>>(xn1, WqT, bqkv, nullptr, nullptr, qkv_h, 3072, 1024);

    // causal attention -> attn (bf16)
    attn_mfma<<<dim3(SEQ / 64, NHEAD, BATCH), 256, 0, stream>>>(qkv_h, attn);

    // x1 = x + attn @ Wo + bo
    gemm128<1><<<dim3(1024 / 128, ROWS / 128), 256, 0, stream>>>(attn, WoT, bo, x, x1, nullptr, 1024, 1024);

    // LN2 -> xn2 (bf16)
    ln_bf16<<<ROWS, 256, 0, stream>>>(x1, ln2w, ln2b, xn2);

    // h = gelu(xn2 @ Wfc + bfc) (bf16)
    gemm128<2><<<dim3(4096 / 128, ROWS / 128), 256, 0, stream>>>(xn2, WfcT, bfc, nullptr, nullptr, hbuf, 4096, 1024);

    // out = x1 + h @ Wproj + bproj
    gemm128<1><<<dim3(1024 / 128, ROWS / 128), 256, 0, stream>>>(hbuf, WpT, bproj, x1, out, nullptr, 1024, 4096);
}

// Round 4
// 346.487 us; speedup vs baseline: 4.9308x; 1.1225x over previous
//
#include <hip/hip_runtime.h>
#include <hip/hip_bf16.h>
#include <math.h>

#define H_DIM 1024
#define SEQ   2048
#define BATCH 2
#define NHEAD 16
#define DKV   64
#define ROWS  (BATCH*SEQ)   // 4096

typedef __attribute__((ext_vector_type(8))) short short8;
typedef __attribute__((ext_vector_type(4))) float f32x4;

static __device__ __forceinline__ unsigned short f32_bf16(float f) {
    unsigned int u = __builtin_bit_cast(unsigned int, f);
    u += 0x7FFF + ((u >> 16) & 1);          // RNE
    return (unsigned short)(u >> 16);
}

static __device__ __forceinline__ void gload16(const unsigned short* g, unsigned short* l) {
    __builtin_amdgcn_global_load_lds(
        (const __attribute__((address_space(1))) void*)g,
        (__attribute__((address_space(3))) void*)l,
        16, 0, 0);
}

// ---------------- fp32 [K][N] -> bf16 [N][K] transpose ----------------
__global__ __launch_bounds__(256) void transpose_bf16(const float* __restrict__ in,
                                                      unsigned short* __restrict__ out,
                                                      int K, int N) {
    __shared__ float tile[32][33];
    int n0 = blockIdx.x * 32, k0 = blockIdx.y * 32;
    int tx = threadIdx.x & 31, ty = threadIdx.x >> 5;   // 32 x 8
    #pragma unroll
    for (int i = 0; i < 4; ++i)
        tile[ty + i * 8][tx] = in[(size_t)(k0 + ty + i * 8) * N + n0 + tx];
    __syncthreads();
    #pragma unroll
    for (int i = 0; i < 4; ++i)
        out[(size_t)(n0 + ty + i * 8) * K + k0 + tx] = f32_bf16(tile[tx][ty + i * 8]);
}

// ---------------- LayerNorm (fp32 in -> bf16 out), one block per row ----------------
__global__ __launch_bounds__(256) void ln_bf16(const float* __restrict__ x,
                                               const float* __restrict__ w,
                                               const float* __restrict__ bb,
                                               unsigned short* __restrict__ out) {
    int row = blockIdx.x;
    int tid = threadIdx.x;
    float4 v = ((const float4*)(x + (size_t)row * H_DIM))[tid];
    float s  = v.x + v.y + v.z + v.w;
    float s2 = v.x*v.x + v.y*v.y + v.z*v.z + v.w*v.w;
    #pragma unroll
    for (int off = 1; off < 64; off <<= 1) {
        s  += __shfl_xor(s,  off, 64);
        s2 += __shfl_xor(s2, off, 64);
    }
    __shared__ float red[8];
    int wv = tid >> 6;
    if ((tid & 63) == 0) { red[wv] = s; red[4 + wv] = s2; }
    __syncthreads();
    s  = red[0] + red[1] + red[2] + red[3];
    s2 = red[4] + red[5] + red[6] + red[7];
    float mu = s * (1.0f / H_DIM);
    float rs = rsqrtf(s2 * (1.0f / H_DIM) - mu * mu + 1e-5f);
    float4 wv4 = ((const float4*)w)[tid];
    float4 bv4 = ((const float4*)bb)[tid];
    ushort4 o;
    o.x = f32_bf16((v.x - mu) * rs * wv4.x + bv4.x);
    o.y = f32_bf16((v.y - mu) * rs * wv4.y + bv4.y);
    o.z = f32_bf16((v.z - mu) * rs * wv4.z + bv4.z);
    o.w = f32_bf16((v.w - mu) * rs * wv4.w + bv4.w);
    ((ushort4*)(out + (size_t)row * H_DIM))[tid] = o;
}

// ---------------- bf16 MFMA GEMM, 128x128 tile, global_load_lds staging ----------------
// EPI 0: outF = acc + bias            (fp32)
// EPI 1: outF = resid + acc + bias    (fp32)
// EPI 2: outH = bf16(gelu(acc+bias))  (bf16)
// EPI 3: outH = bf16(acc+bias)        (bf16)
// EPI 4: QKV special: cols<2048 -> outH [row][2048]; cols>=2048 (V) -> outH2 transposed [b*1024+hd][2048]+s
template<int EPI>
__global__ __launch_bounds__(256) void gemm128(const unsigned short* __restrict__ A,
                                               const unsigned short* __restrict__ Bt,
                                               const float* __restrict__ bias,
                                               const float* __restrict__ resid,
                                               float* __restrict__ outF,
                                               unsigned short* __restrict__ outH,
                                               unsigned short* __restrict__ outH2,
                                               int N, int K) {
    __shared__ __attribute__((aligned(16))) unsigned short As[128][32];
    __shared__ __attribute__((aligned(16))) unsigned short Bs[128][32];
    int tid = threadIdx.x;
    int w = tid >> 6, l = tid & 63;
    int l15 = l & 15, lg = l >> 4;
    int wm = w & 1, wn = w >> 1;
    int m0 = blockIdx.y * 128, n0 = blockIdx.x * 128;

    f32x4 acc[4][4] = {};

    int idx0 = (w * 2 + 0) * 64 + l;
    int idx1 = (w * 2 + 1) * 64 + l;
    const unsigned short* a0 = A  + (size_t)(m0 + (idx0 >> 2)) * K + (idx0 & 3) * 8;
    const unsigned short* a1 = A  + (size_t)(m0 + (idx1 >> 2)) * K + (idx1 & 3) * 8;
    const unsigned short* b0 = Bt + (size_t)(n0 + (idx0 >> 2)) * K + (idx0 & 3) * 8;
    const unsigned short* b1 = Bt + (size_t)(n0 + (idx1 >> 2)) * K + (idx1 & 3) * 8;
    unsigned short* lA0 = &As[0][0] + (w * 2 + 0) * 512;
    unsigned short* lA1 = &As[0][0] + (w * 2 + 1) * 512;
    unsigned short* lB0 = &Bs[0][0] + (w * 2 + 0) * 512;
    unsigned short* lB1 = &Bs[0][0] + (w * 2 + 1) * 512;

    for (int k0 = 0; k0 < K; k0 += 32) {
        __syncthreads();
        gload16(a0 + k0, lA0);
        gload16(a1 + k0, lA1);
        gload16(b0 + k0, lB0);
        gload16(b1 + k0, lB1);
        __syncthreads();

        short8 af[4], bf[4];
        #pragma unroll
        for (int mi = 0; mi < 4; ++mi)
            af[mi] = *(const short8*)&As[wm * 64 + mi * 16 + l15][lg * 8];
        #pragma unroll
        for (int ni = 0; ni < 4; ++ni)
            bf[ni] = *(const short8*)&Bs[wn * 64 + ni * 16 + l15][lg * 8];
        #pragma unroll
        for (int mi = 0; mi < 4; ++mi)
            #pragma unroll
            for (int ni = 0; ni < 4; ++ni)
                acc[mi][ni] = __builtin_amdgcn_mfma_f32_16x16x32_bf16(af[mi], bf[ni], acc[mi][ni], 0, 0, 0);
    }

    #pragma unroll
    for (int mi = 0; mi < 4; ++mi) {
        #pragma unroll
        for (int ni = 0; ni < 4; ++ni) {
            int col = n0 + wn * 64 + ni * 16 + l15;
            float bv = bias[col];
            #pragma unroll
            for (int j = 0; j < 4; ++j) {
                int row = m0 + wm * 64 + mi * 16 + lg * 4 + j;
                size_t idx = (size_t)row * N + col;
                float c = acc[mi][ni][j] + bv;
                if (EPI == 0) {
                    outF[idx] = c;
                } else if (EPI == 1) {
                    outF[idx] = resid[idx] + c;
                } else if (EPI == 2) {
                    float g = 0.5f * c * (1.0f + erff(c * 0.70710678118f));
                    outH[idx] = f32_bf16(g);
                } else if (EPI == 3) {
                    outH[idx] = f32_bf16(c);
                } else {
                    unsigned short hv = f32_bf16(c);
                    if (col < 2048) {
                        outH[(size_t)row * 2048 + col] = hv;           // Q|K packed
                    } else {
                        int bb = row >> 11, ss = row & 2047;
                        int hd = col - 2048;                            // h*64+d
                        outH2[((size_t)bb * 1024 + hd) * SEQ + ss] = hv; // V transposed
                    }
                }
            }
        }
    }
}

// ---------------- causal flash attention, MFMA 16x16x32 bf16 ----------------
// qk: bf16 [ROWS][2048] (Q | K); vT: bf16 [B*NH*DKV][SEQ] (V transposed).
// Flat grid 1024 = B*NH*(SEQ/64), XCD-swizzled so 4 (b,h) groups share an XCD.
__global__ __launch_bounds__(256) void attn_mfma(const unsigned short* __restrict__ qk,
                                                 const unsigned short* __restrict__ vT,
                                                 unsigned short* __restrict__ out) {
    int bid = blockIdx.x;
    int swz = (bid & 7) * 128 + (bid >> 3);   // 1024 % 8 == 0 -> bijective
    int b  = swz >> 9;
    int h  = (swz >> 5) & 15;
    int qt = 31 - (swz & 31);                 // long blocks first within group
    int tid = threadIdx.x;
    int w = tid >> 6, l = tid & 63;
    int l15 = l & 15, lg = l >> 4;

    __shared__ __attribute__((aligned(16))) unsigned short Ks[64][72];
    __shared__ __attribute__((aligned(16))) unsigned short Vt[64][72];  // Vt[d][k]
    __shared__ __attribute__((aligned(16))) unsigned short Ps[4][16][72];

    // Q fragments: lane l holds Q[q=l15][d = dstep*32 + lg*8 + 0..7]
    short8 qf[2];
    {
        int qrow = qt * 64 + w * 16 + l15;
        const unsigned short* qp = qk + (size_t)(b * SEQ + qrow) * 2048 + h * DKV + lg * 8;
        qf[0] = *(const short8*)qp;
        qf[1] = *(const short8*)(qp + 32);
    }

    // staging addresses: wave w stages rows/d-rows w*16..+15, 4 lanes x 16 elems each
    int srow = l >> 2;
    int scol = (l & 3) * 16;
    int krow = w * 16 + srow;
    const unsigned short* kbase = qk + (size_t)(b * SEQ + krow) * 2048 + 1024 + h * DKV + scol;
    const unsigned short* vbase = vT + ((size_t)(b * NHEAD + h) * DKV + krow) * SEQ + scol;

    // prefetch tile 0 into registers (T14 async-stage split)
    short8 kr0 = *(const short8*)kbase;
    short8 kr1 = *(const short8*)(kbase + 8);
    short8 vr0 = *(const short8*)vbase;
    short8 vr1 = *(const short8*)(vbase + 8);

    float m[4], lsum[4];
    f32x4 oacc[4] = {};
    #pragma unroll
    for (int j = 0; j < 4; ++j) { m[j] = -1e30f; lsum[j] = 0.0f; }

    for (int kt = 0; kt <= qt; ++kt) {
        __syncthreads();   // previous tile's LDS reads complete
        *(short8*)&Ks[krow][scol]     = kr0;
        *(short8*)&Ks[krow][scol + 8] = kr1;
        *(short8*)&Vt[krow][scol]     = vr0;
        *(short8*)&Vt[krow][scol + 8] = vr1;
        __syncthreads();   // staged tile visible
        if (kt < qt) {     // issue next-tile loads; land during compute below
            const unsigned short* kp = kbase + (size_t)(kt + 1) * 64 * 2048;
            const unsigned short* vp = vbase + (kt + 1) * 64;
            kr0 = *(const short8*)kp;
            kr1 = *(const short8*)(kp + 8);
            vr0 = *(const short8*)vp;
            vr1 = *(const short8*)(vp + 8);
        }

        // QK^T
        f32x4 sc[4] = {};
        __builtin_amdgcn_s_setprio(1);
        #pragma unroll
        for (int dstep = 0; dstep < 2; ++dstep) {
            #pragma unroll
            for (int st = 0; st < 4; ++st) {
                short8 kf = *(const short8*)&Ks[st * 16 + l15][dstep * 32 + lg * 8];
                sc[st] = __builtin_amdgcn_mfma_f32_16x16x32_bf16(qf[dstep], kf, sc[st], 0, 0, 0);
            }
        }
        __builtin_amdgcn_s_setprio(0);

        // mask + online softmax (C layout: row=q=lg*4+j, col=k=l15+st*16)
        int qglob = qt * 64 + w * 16 + lg * 4;
        int kcol  = kt * 64 + l15;
        bool diag = (kt == qt);
        float pv[4][4];
        float scale[4];
        #pragma unroll
        for (int j = 0; j < 4; ++j) {
            float mx = -1e30f;
            #pragma unroll
            for (int st = 0; st < 4; ++st) {
                float s = sc[st][j] * 0.125f;
                if (diag && (kcol + st * 16 > qglob + j)) s = -1e30f;
                pv[st][j] = s;
                mx = fmaxf(mx, s);
            }
            mx = fmaxf(mx, __shfl_xor(mx, 1, 64));
            mx = fmaxf(mx, __shfl_xor(mx, 2, 64));
            mx = fmaxf(mx, __shfl_xor(mx, 4, 64));
            mx = fmaxf(mx, __shfl_xor(mx, 8, 64));
            float mn = fmaxf(m[j], mx);
            scale[j] = __expf(m[j] - mn);
            float ps = 0.0f;
            #pragma unroll
            for (int st = 0; st < 4; ++st) {
                float p = __expf(pv[st][j] - mn);
                pv[st][j] = p;
                ps += p;
            }
            ps += __shfl_xor(ps, 1, 64);
            ps += __shfl_xor(ps, 2, 64);
            ps += __shfl_xor(ps, 4, 64);
            ps += __shfl_xor(ps, 8, 64);
            lsum[j] = lsum[j] * scale[j] + ps;
            m[j] = mn;
        }

        // P -> per-wave LDS (re-layout to A-fragment)
        #pragma unroll
        for (int st = 0; st < 4; ++st)
            #pragma unroll
            for (int j = 0; j < 4; ++j)
                Ps[w][lg * 4 + j][st * 16 + l15] = f32_bf16(pv[st][j]);

        // rescale O
        #pragma unroll
        for (int d = 0; d < 4; ++d)
            #pragma unroll
            for (int j = 0; j < 4; ++j)
                oacc[d][j] *= scale[j];

        // PV
        __builtin_amdgcn_s_setprio(1);
        #pragma unroll
        for (int ks = 0; ks < 2; ++ks) {
            short8 pf = *(const short8*)&Ps[w][l15][ks * 32 + lg * 8];
            #pragma unroll
            for (int d = 0; d < 4; ++d) {
                short8 vf = *(const short8*)&Vt[d * 16 + l15][ks * 32 + lg * 8];
                oacc[d] = __builtin_amdgcn_mfma_f32_16x16x32_bf16(pf, vf, oacc[d], 0, 0, 0);
            }
        }
        __builtin_amdgcn_s_setprio(0);
    }

    #pragma unroll
    for (int j = 0; j < 4; ++j) {
        float inv = 1.0f / lsum[j];
        int qrow = qt * 64 + w * 16 + lg * 4 + j;
        size_t ob = (size_t)(b * SEQ + qrow) * H_DIM + h * DKV;
        #pragma unroll
        for (int d = 0; d < 4; ++d)
            out[ob + d * 16 + l15] = f32_bf16(oacc[d][j] * inv);
    }
}

// ---------------- launch ----------------
extern "C" void kernel_launch(void* const* d_in, const int* in_sizes, int n_in,
                              void* d_out, int out_size, void* d_ws, size_t ws_size,
                              hipStream_t stream) {
    const float* x     = (const float*)d_in[0];
    const float* ln1w  = (const float*)d_in[1];
    const float* ln1b  = (const float*)d_in[2];
    const float* Wqkv  = (const float*)d_in[3];
    const float* bqkv  = (const float*)d_in[4];
    const float* Wo    = (const float*)d_in[5];
    const float* bo    = (const float*)d_in[6];
    const float* ln2w  = (const float*)d_in[7];
    const float* ln2b  = (const float*)d_in[8];
    const float* Wfc   = (const float*)d_in[9];
    const float* bfc   = (const float*)d_in[10];
    const float* Wproj = (const float*)d_in[11];
    const float* bproj = (const float*)d_in[12];
    float* out = (float*)d_out;

    char* ws = (char*)d_ws;
    size_t off = 0;
    auto take = [&](size_t bytes) {
        void* p = ws + off;
        off += (bytes + 255) & ~(size_t)255;
        return p;
    };

    unsigned short* WqT  = (unsigned short*)take((size_t)3072 * 1024 * 2);
    unsigned short* WoT  = (unsigned short*)take((size_t)1024 * 1024 * 2);
    unsigned short* WfcT = (unsigned short*)take((size_t)4096 * 1024 * 2);
    unsigned short* WpT  = (unsigned short*)take((size_t)1024 * 4096 * 2);
    unsigned short* xn1   = (unsigned short*)take((size_t)ROWS * 1024 * 2);
    unsigned short* qk_h  = (unsigned short*)take((size_t)ROWS * 2048 * 2);
    unsigned short* vT    = (unsigned short*)take((size_t)ROWS * 1024 * 2);   // [B*NH*DKV][SEQ]
    unsigned short* attn  = (unsigned short*)take((size_t)ROWS * 1024 * 2);
    float*          x1    = (float*)take((size_t)ROWS * 1024 * 4);
    unsigned short* xn2   = (unsigned short*)take((size_t)ROWS * 1024 * 2);
    unsigned short* hbuf  = (unsigned short*)take((size_t)ROWS * 4096 * 2);

    // weight transposes fp32[K][N] -> bf16[N][K]
    transpose_bf16<<<dim3(3072 / 32, 1024 / 32), 256, 0, stream>>>(Wqkv,  WqT,  1024, 3072);
    transpose_bf16<<<dim3(1024 / 32, 1024 / 32), 256, 0, stream>>>(Wo,    WoT,  1024, 1024);
    transpose_bf16<<<dim3(4096 / 32, 1024 / 32), 256, 0, stream>>>(Wfc,   WfcT, 1024, 4096);
    transpose_bf16<<<dim3(1024 / 32, 4096 / 32), 256, 0, stream>>>(Wproj, WpT,  4096, 1024);

    // LN1 -> xn1 (bf16)
    ln_bf16<<<ROWS, 256, 0, stream>>>(x, ln1w, ln1b, xn1);

    // QKV: Q|K -> qk_h packed, V -> vT transposed
    gemm128<4><<<dim3(3072 / 128, ROWS / 128), 256, 0, stream>>>(xn1, WqT, bqkv, nullptr, nullptr, qk_h, vT, 3072, 1024);

    // causal attention -> attn (bf16)
    attn_mfma<<<1024, 256, 0, stream>>>(qk_h, vT, attn);

    // x1 = x + attn @ Wo + bo
    gemm128<1><<<dim3(1024 / 128, ROWS / 128), 256, 0, stream>>>(attn, WoT, bo, x, x1, nullptr, nullptr, 1024, 1024);

    // LN2 -> xn2 (bf16)
    ln_bf16<<<ROWS, 256, 0, stream>>>(x1, ln2w, ln2b, xn2);

    // h = gelu(xn2 @ Wfc + bfc) (bf16)
    gemm128<2><<<dim3(4096 / 128, ROWS / 128), 256, 0, stream>>>(xn2, WfcT, bfc, nullptr, nullptr, hbuf, nullptr, 4096, 1024);

    // out = x1 + h @ Wproj + bproj
    gemm128<1><<<dim3(1024 / 128, ROWS / 128), 256, 0, stream>>>(hbuf, WpT, bproj, x1, out, nullptr, nullptr, 1024, 4096);
}

// Round 5
// 305.667 us; speedup vs baseline: 5.5893x; 1.1335x over previous
//
#include <hip/hip_runtime.h>
#include <hip/hip_bf16.h>
#include <math.h>

#define H_DIM 1024
#define SEQ   2048
#define BATCH 2
#define NHEAD 16
#define DKV   64
#define ROWS  (BATCH*SEQ)   // 4096

typedef __attribute__((ext_vector_type(8))) short short8;
typedef __attribute__((ext_vector_type(4))) float f32x4;

static __device__ __forceinline__ unsigned short f32_bf16(float f) {
    unsigned int u = __builtin_bit_cast(unsigned int, f);
    u += 0x7FFF + ((u >> 16) & 1);          // RNE
    return (unsigned short)(u >> 16);
}

// A&S 7.1.26 rational-poly erf, |err| < 1.5e-7 (way below bf16 rounding)
static __device__ __forceinline__ float fast_erf(float x) {
    float ax = fabsf(x);
    float t = 1.0f / fmaf(0.3275911f, ax, 1.0f);
    float p = t * fmaf(t, fmaf(t, fmaf(t, fmaf(t, 1.061405429f, -1.453152027f),
                                       1.421413741f), -0.284496736f), 0.254829592f);
    float y = fmaf(-p, __expf(-ax * ax), 1.0f);
    return copysignf(y, x);
}

static __device__ __forceinline__ void gload16(const unsigned short* g, unsigned short* l) {
    __builtin_amdgcn_global_load_lds(
        (const __attribute__((address_space(1))) void*)g,
        (__attribute__((address_space(3))) void*)l,
        16, 0, 0);
}

// ---------------- fp32 [K][N] -> bf16 [N][K] transpose ----------------
__global__ __launch_bounds__(256) void transpose_bf16(const float* __restrict__ in,
                                                      unsigned short* __restrict__ out,
                                                      int K, int N) {
    __shared__ float tile[32][33];
    int n0 = blockIdx.x * 32, k0 = blockIdx.y * 32;
    int tx = threadIdx.x & 31, ty = threadIdx.x >> 5;   // 32 x 8
    #pragma unroll
    for (int i = 0; i < 4; ++i)
        tile[ty + i * 8][tx] = in[(size_t)(k0 + ty + i * 8) * N + n0 + tx];
    __syncthreads();
    #pragma unroll
    for (int i = 0; i < 4; ++i)
        out[(size_t)(n0 + ty + i * 8) * K + k0 + tx] = f32_bf16(tile[tx][ty + i * 8]);
}

// ---------------- LayerNorm (fp32 in -> bf16 out), one block per row ----------------
__global__ __launch_bounds__(256) void ln_bf16(const float* __restrict__ x,
                                               const float* __restrict__ w,
                                               const float* __restrict__ bb,
                                               unsigned short* __restrict__ out) {
    int row = blockIdx.x;
    int tid = threadIdx.x;
    float4 v = ((const float4*)(x + (size_t)row * H_DIM))[tid];
    float s  = v.x + v.y + v.z + v.w;
    float s2 = v.x*v.x + v.y*v.y + v.z*v.z + v.w*v.w;
    #pragma unroll
    for (int off = 1; off < 64; off <<= 1) {
        s  += __shfl_xor(s,  off, 64);
        s2 += __shfl_xor(s2, off, 64);
    }
    __shared__ float red[8];
    int wv = tid >> 6;
    if ((tid & 63) == 0) { red[wv] = s; red[4 + wv] = s2; }
    __syncthreads();
    s  = red[0] + red[1] + red[2] + red[3];
    s2 = red[4] + red[5] + red[6] + red[7];
    float mu = s * (1.0f / H_DIM);
    float rs = rsqrtf(s2 * (1.0f / H_DIM) - mu * mu + 1e-5f);
    float4 wv4 = ((const float4*)w)[tid];
    float4 bv4 = ((const float4*)bb)[tid];
    ushort4 o;
    o.x = f32_bf16((v.x - mu) * rs * wv4.x + bv4.x);
    o.y = f32_bf16((v.y - mu) * rs * wv4.y + bv4.y);
    o.z = f32_bf16((v.z - mu) * rs * wv4.z + bv4.z);
    o.w = f32_bf16((v.w - mu) * rs * wv4.w + bv4.w);
    ((ushort4*)(out + (size_t)row * H_DIM))[tid] = o;
}

// ---------------- bf16 MFMA GEMM, 128x128 tile, BK=64, swizzled LDS ----------------
// LDS chunk swizzle (16B granularity, involution within each 128B row):
//   physical_chunk = logical_chunk ^ (row & 7)
// global_load_lds dest stays LINEAR; the per-lane GLOBAL address is pre-swizzled
// (m201 pattern), and ds_read applies the same XOR -> 2-way conflicts only.
// EPI 0: outF = acc + bias            (fp32)
// EPI 1: outF = resid + acc + bias    (fp32)
// EPI 2: outH = bf16(gelu(acc+bias))  (bf16)
// EPI 3: outH = bf16(acc+bias)        (bf16)
// EPI 4: QKV: cols<2048 -> outH [row][2048]; cols>=2048 (V) -> outH2 [b*1024+hd][SEQ] (transposed, ushort4)
template<int EPI>
__global__ __launch_bounds__(256) void gemm128(const unsigned short* __restrict__ A,
                                               const unsigned short* __restrict__ Bt,
                                               const float* __restrict__ bias,
                                               const float* __restrict__ resid,
                                               float* __restrict__ outF,
                                               unsigned short* __restrict__ outH,
                                               unsigned short* __restrict__ outH2,
                                               int N, int K) {
    __shared__ __attribute__((aligned(16))) unsigned short As[128][64];
    __shared__ __attribute__((aligned(16))) unsigned short Bs[128][64];
    int tid = threadIdx.x;
    int w = tid >> 6, l = tid & 63;
    int l15 = l & 15, lg = l >> 4;
    int wm = w & 1, wn = w >> 1;
    int m0 = blockIdx.y * 128, n0 = blockIdx.x * 128;

    f32x4 acc[4][4] = {};

    // staging: thread issues 4 A + 4 B gload16; slot j covers LDS chunks (w*4+j)*64 + l
    const unsigned short* aptr[4];
    const unsigned short* bptr[4];
    unsigned short* lA[4];
    unsigned short* lB[4];
    #pragma unroll
    for (int j = 0; j < 4; ++j) {
        int slot = (w * 4 + j) * 64 + l;          // 0..1023
        int row = slot >> 3;
        int lchunk = (slot & 7) ^ (row & 7);      // source chunk for this physical slot
        aptr[j] = A  + (size_t)(m0 + row) * K + lchunk * 8;
        bptr[j] = Bt + (size_t)(n0 + row) * K + lchunk * 8;
        lA[j] = &As[0][0] + (w * 4 + j) * 512;    // + lane*16B by HW
        lB[j] = &Bs[0][0] + (w * 4 + j) * 512;
    }
    // reader bases: row = (wm|wn)*64 + mi*16 + l15 ; row&7 == l15&7
    int swz[2];
    swz[0] = ((0 + lg) ^ (l15 & 7)) * 8;          // ks=0: logical chunk lg
    swz[1] = ((4 + lg) ^ (l15 & 7)) * 8;          // ks=1: logical chunk 4+lg
    const unsigned short* pA = &As[wm * 64 + l15][0];
    const unsigned short* pB = &Bs[wn * 64 + l15][0];

    for (int k0 = 0; k0 < K; k0 += 64) {
        __syncthreads();
        #pragma unroll
        for (int j = 0; j < 4; ++j) gload16(aptr[j] + k0, lA[j]);
        #pragma unroll
        for (int j = 0; j < 4; ++j) gload16(bptr[j] + k0, lB[j]);
        __syncthreads();

        #pragma unroll
        for (int ks = 0; ks < 2; ++ks) {
            short8 af[4], bf[4];
            #pragma unroll
            for (int mi = 0; mi < 4; ++mi)
                af[mi] = *(const short8*)(pA + mi * 16 * 64 + swz[ks]);
            #pragma unroll
            for (int ni = 0; ni < 4; ++ni)
                bf[ni] = *(const short8*)(pB + ni * 16 * 64 + swz[ks]);
            #pragma unroll
            for (int mi = 0; mi < 4; ++mi)
                #pragma unroll
                for (int ni = 0; ni < 4; ++ni)
                    acc[mi][ni] = __builtin_amdgcn_mfma_f32_16x16x32_bf16(af[mi], bf[ni], acc[mi][ni], 0, 0, 0);
        }
    }

    #pragma unroll
    for (int mi = 0; mi < 4; ++mi) {
        #pragma unroll
        for (int ni = 0; ni < 4; ++ni) {
            int col = n0 + wn * 64 + ni * 16 + l15;
            float bv = bias[col];
            if (EPI == 4 && col >= 2048) {
                // V head: rows lg*4..+3 are consecutive s -> one ushort4 store
                int row0 = m0 + wm * 64 + mi * 16 + lg * 4;
                int bb = row0 >> 11, ss = row0 & 2047;
                int hd = col - 2048;
                ushort4 u;
                u.x = f32_bf16(acc[mi][ni][0] + bv);
                u.y = f32_bf16(acc[mi][ni][1] + bv);
                u.z = f32_bf16(acc[mi][ni][2] + bv);
                u.w = f32_bf16(acc[mi][ni][3] + bv);
                *(ushort4*)&outH2[((size_t)bb * 1024 + hd) * SEQ + ss] = u;
            } else {
                #pragma unroll
                for (int j = 0; j < 4; ++j) {
                    int row = m0 + wm * 64 + mi * 16 + lg * 4 + j;
                    size_t idx = (size_t)row * N + col;
                    float c = acc[mi][ni][j] + bv;
                    if (EPI == 0) {
                        outF[idx] = c;
                    } else if (EPI == 1) {
                        outF[idx] = resid[idx] + c;
                    } else if (EPI == 2) {
                        float g = 0.5f * c * (1.0f + fast_erf(c * 0.70710678118f));
                        outH[idx] = f32_bf16(g);
                    } else if (EPI == 3) {
                        outH[idx] = f32_bf16(c);
                    } else {
                        outH[(size_t)row * 2048 + col] = f32_bf16(c);   // Q|K packed
                    }
                }
            }
        }
    }
}

// ---------------- causal flash attention, MFMA 16x16x32 bf16 ----------------
// qk: bf16 [ROWS][2048] (Q | K); vT: bf16 [B*NH*DKV][SEQ] (V transposed).
__global__ __launch_bounds__(256) void attn_mfma(const unsigned short* __restrict__ qk,
                                                 const unsigned short* __restrict__ vT,
                                                 unsigned short* __restrict__ out) {
    int bid = blockIdx.x;
    int swz = (bid & 7) * 128 + (bid >> 3);   // 1024 % 8 == 0 -> bijective
    int b  = swz >> 9;
    int h  = (swz >> 5) & 15;
    int qt = 31 - (swz & 31);                 // long blocks first within group
    int tid = threadIdx.x;
    int w = tid >> 6, l = tid & 63;
    int l15 = l & 15, lg = l >> 4;

    __shared__ __attribute__((aligned(16))) unsigned short Ks[64][72];
    __shared__ __attribute__((aligned(16))) unsigned short Vt[64][72];  // Vt[d][k]
    __shared__ __attribute__((aligned(16))) unsigned short Ps[4][16][72];

    short8 qf[2];
    {
        int qrow = qt * 64 + w * 16 + l15;
        const unsigned short* qp = qk + (size_t)(b * SEQ + qrow) * 2048 + h * DKV + lg * 8;
        qf[0] = *(const short8*)qp;
        qf[1] = *(const short8*)(qp + 32);
    }

    int srow = l >> 2;
    int scol = (l & 3) * 16;
    int krow = w * 16 + srow;
    const unsigned short* kbase = qk + (size_t)(b * SEQ + krow) * 2048 + 1024 + h * DKV + scol;
    const unsigned short* vbase = vT + ((size_t)(b * NHEAD + h) * DKV + krow) * SEQ + scol;

    short8 kr0 = *(const short8*)kbase;
    short8 kr1 = *(const short8*)(kbase + 8);
    short8 vr0 = *(const short8*)vbase;
    short8 vr1 = *(const short8*)(vbase + 8);

    float m[4], lsum[4];
    f32x4 oacc[4] = {};
    #pragma unroll
    for (int j = 0; j < 4; ++j) { m[j] = -1e30f; lsum[j] = 0.0f; }

    for (int kt = 0; kt <= qt; ++kt) {
        __syncthreads();
        *(short8*)&Ks[krow][scol]     = kr0;
        *(short8*)&Ks[krow][scol + 8] = kr1;
        *(short8*)&Vt[krow][scol]     = vr0;
        *(short8*)&Vt[krow][scol + 8] = vr1;
        __syncthreads();
        if (kt < qt) {
            const unsigned short* kp = kbase + (size_t)(kt + 1) * 64 * 2048;
            const unsigned short* vp = vbase + (kt + 1) * 64;
            kr0 = *(const short8*)kp;
            kr1 = *(const short8*)(kp + 8);
            vr0 = *(const short8*)vp;
            vr1 = *(const short8*)(vp + 8);
        }

        f32x4 sc[4] = {};
        __builtin_amdgcn_s_setprio(1);
        #pragma unroll
        for (int dstep = 0; dstep < 2; ++dstep) {
            #pragma unroll
            for (int st = 0; st < 4; ++st) {
                short8 kf = *(const short8*)&Ks[st * 16 + l15][dstep * 32 + lg * 8];
                sc[st] = __builtin_amdgcn_mfma_f32_16x16x32_bf16(qf[dstep], kf, sc[st], 0, 0, 0);
            }
        }
        __builtin_amdgcn_s_setprio(0);

        int qglob = qt * 64 + w * 16 + lg * 4;
        int kcol  = kt * 64 + l15;
        bool diag = (kt == qt);
        float pv[4][4];
        float scale[4];
        #pragma unroll
        for (int j = 0; j < 4; ++j) {
            float mx = -1e30f;
            #pragma unroll
            for (int st = 0; st < 4; ++st) {
                float s = sc[st][j] * 0.125f;
                if (diag && (kcol + st * 16 > qglob + j)) s = -1e30f;
                pv[st][j] = s;
                mx = fmaxf(mx, s);
            }
            mx = fmaxf(mx, __shfl_xor(mx, 1, 64));
            mx = fmaxf(mx, __shfl_xor(mx, 2, 64));
            mx = fmaxf(mx, __shfl_xor(mx, 4, 64));
            mx = fmaxf(mx, __shfl_xor(mx, 8, 64));
            float mn = fmaxf(m[j], mx);
            scale[j] = __expf(m[j] - mn);
            float ps = 0.0f;
            #pragma unroll
            for (int st = 0; st < 4; ++st) {
                float p = __expf(pv[st][j] - mn);
                pv[st][j] = p;
                ps += p;
            }
            ps += __shfl_xor(ps, 1, 64);
            ps += __shfl_xor(ps, 2, 64);
            ps += __shfl_xor(ps, 4, 64);
            ps += __shfl_xor(ps, 8, 64);
            lsum[j] = lsum[j] * scale[j] + ps;
            m[j] = mn;
        }

        #pragma unroll
        for (int st = 0; st < 4; ++st)
            #pragma unroll
            for (int j = 0; j < 4; ++j)
                Ps[w][lg * 4 + j][st * 16 + l15] = f32_bf16(pv[st][j]);

        #pragma unroll
        for (int d = 0; d < 4; ++d)
            #pragma unroll
            for (int j = 0; j < 4; ++j)
                oacc[d][j] *= scale[j];

        __builtin_amdgcn_s_setprio(1);
        #pragma unroll
        for (int ks = 0; ks < 2; ++ks) {
            short8 pf = *(const short8*)&Ps[w][l15][ks * 32 + lg * 8];
            #pragma unroll
            for (int d = 0; d < 4; ++d) {
                short8 vf = *(const short8*)&Vt[d * 16 + l15][ks * 32 + lg * 8];
                oacc[d] = __builtin_amdgcn_mfma_f32_16x16x32_bf16(pf, vf, oacc[d], 0, 0, 0);
            }
        }
        __builtin_amdgcn_s_setprio(0);
    }

    #pragma unroll
    for (int j = 0; j < 4; ++j) {
        float inv = 1.0f / lsum[j];
        int qrow = qt * 64 + w * 16 + lg * 4 + j;
        size_t ob = (size_t)(b * SEQ + qrow) * H_DIM + h * DKV;
        #pragma unroll
        for (int d = 0; d < 4; ++d)
            out[ob + d * 16 + l15] = f32_bf16(oacc[d][j] * inv);
    }
}

// ---------------- launch ----------------
extern "C" void kernel_launch(void* const* d_in, const int* in_sizes, int n_in,
                              void* d_out, int out_size, void* d_ws, size_t ws_size,
                              hipStream_t stream) {
    const float* x     = (const float*)d_in[0];
    const float* ln1w  = (const float*)d_in[1];
    const float* ln1b  = (const float*)d_in[2];
    const float* Wqkv  = (const float*)d_in[3];
    const float* bqkv  = (const float*)d_in[4];
    const float* Wo    = (const float*)d_in[5];
    const float* bo    = (const float*)d_in[6];
    const float* ln2w  = (const float*)d_in[7];
    const float* ln2b  = (const float*)d_in[8];
    const float* Wfc   = (const float*)d_in[9];
    const float* bfc   = (const float*)d_in[10];
    const float* Wproj = (const float*)d_in[11];
    const float* bproj = (const float*)d_in[12];
    float* out = (float*)d_out;

    char* ws = (char*)d_ws;
    size_t off = 0;
    auto take = [&](size_t bytes) {
        void* p = ws + off;
        off += (bytes + 255) & ~(size_t)255;
        return p;
    };

    unsigned short* WqT  = (unsigned short*)take((size_t)3072 * 1024 * 2);
    unsigned short* WoT  = (unsigned short*)take((size_t)1024 * 1024 * 2);
    unsigned short* WfcT = (unsigned short*)take((size_t)4096 * 1024 * 2);
    unsigned short* WpT  = (unsigned short*)take((size_t)1024 * 4096 * 2);
    unsigned short* xn1   = (unsigned short*)take((size_t)ROWS * 1024 * 2);
    unsigned short* qk_h  = (unsigned short*)take((size_t)ROWS * 2048 * 2);
    unsigned short* vT    = (unsigned short*)take((size_t)ROWS * 1024 * 2);   // [B*NH*DKV][SEQ]
    unsigned short* attn  = (unsigned short*)take((size_t)ROWS * 1024 * 2);
    float*          x1    = (float*)take((size_t)ROWS * 1024 * 4);
    unsigned short* xn2   = (unsigned short*)take((size_t)ROWS * 1024 * 2);
    unsigned short* hbuf  = (unsigned short*)take((size_t)ROWS * 4096 * 2);

    // weight transposes fp32[K][N] -> bf16[N][K]
    transpose_bf16<<<dim3(3072 / 32, 1024 / 32), 256, 0, stream>>>(Wqkv,  WqT,  1024, 3072);
    transpose_bf16<<<dim3(1024 / 32, 1024 / 32), 256, 0, stream>>>(Wo,    WoT,  1024, 1024);
    transpose_bf16<<<dim3(4096 / 32, 1024 / 32), 256, 0, stream>>>(Wfc,   WfcT, 1024, 4096);
    transpose_bf16<<<dim3(1024 / 32, 4096 / 32), 256, 0, stream>>>(Wproj, WpT,  4096, 1024);

    // LN1 -> xn1 (bf16)
    ln_bf16<<<ROWS, 256, 0, stream>>>(x, ln1w, ln1b, xn1);

    // QKV: Q|K -> qk_h packed, V -> vT transposed
    gemm128<4><<<dim3(3072 / 128, ROWS / 128), 256, 0, stream>>>(xn1, WqT, bqkv, nullptr, nullptr, qk_h, vT, 3072, 1024);

    // causal attention -> attn (bf16)
    attn_mfma<<<1024, 256, 0, stream>>>(qk_h, vT, attn);

    // x1 = x + attn @ Wo + bo
    gemm128<1><<<dim3(1024 / 128, ROWS / 128), 256, 0, stream>>>(attn, WoT, bo, x, x1, nullptr, nullptr, 1024, 1024);

    // LN2 -> xn2 (bf16)
    ln_bf16<<<ROWS, 256, 0, stream>>>(x1, ln2w, ln2b, xn2);

    // h = gelu(xn2 @ Wfc + bfc) (bf16)
    gemm128<2><<<dim3(4096 / 128, ROWS / 128), 256, 0, stream>>>(xn2, WfcT, bfc, nullptr, nullptr, hbuf, nullptr, 4096, 1024);

    // out = x1 + h @ Wproj + bproj
    gemm128<1><<<dim3(1024 / 128, ROWS / 128), 256, 0, stream>>>(hbuf, WpT, bproj, x1, out, nullptr, nullptr, 1024, 4096);
}

// Round 7
// 287.364 us; speedup vs baseline: 5.9453x; 1.0637x over previous
//
#include <hip/hip_runtime.h>
#include <hip/hip_bf16.h>
#include <math.h>

#define H_DIM 1024
#define SEQ   2048
#define BATCH 2
#define NHEAD 16
#define DKV   64
#define ROWS  (BATCH*SEQ)   // 4096

typedef __attribute__((ext_vector_type(8))) short short8;
typedef __attribute__((ext_vector_type(4))) float f32x4;

static __device__ __forceinline__ unsigned short f32_bf16(float f) {
    unsigned int u = __builtin_bit_cast(unsigned int, f);
    u += 0x7FFF + ((u >> 16) & 1);          // RNE
    return (unsigned short)(u >> 16);
}

// A&S 7.1.26 rational-poly erf, |err| < 1.5e-7 (way below bf16 rounding)
static __device__ __forceinline__ float fast_erf(float x) {
    float ax = fabsf(x);
    float t = 1.0f / fmaf(0.3275911f, ax, 1.0f);
    float p = t * fmaf(t, fmaf(t, fmaf(t, fmaf(t, 1.061405429f, -1.453152027f),
                                       1.421413741f), -0.284496736f), 0.254829592f);
    float y = fmaf(-p, __expf(-ax * ax), 1.0f);
    return copysignf(y, x);
}

static __device__ __forceinline__ void gload16(const unsigned short* g, unsigned short* l) {
    __builtin_amdgcn_global_load_lds(
        (const __attribute__((address_space(1))) void*)g,
        (__attribute__((address_space(3))) void*)l,
        16, 0, 0);
}

// ---------------- fp32 [K][N] -> bf16 [N][K] transpose ----------------
__global__ __launch_bounds__(256) void transpose_bf16(const float* __restrict__ in,
                                                      unsigned short* __restrict__ out,
                                                      int K, int N) {
    __shared__ float tile[32][33];
    int n0 = blockIdx.x * 32, k0 = blockIdx.y * 32;
    int tx = threadIdx.x & 31, ty = threadIdx.x >> 5;   // 32 x 8
    #pragma unroll
    for (int i = 0; i < 4; ++i)
        tile[ty + i * 8][tx] = in[(size_t)(k0 + ty + i * 8) * N + n0 + tx];
    __syncthreads();
    #pragma unroll
    for (int i = 0; i < 4; ++i)
        out[(size_t)(n0 + ty + i * 8) * K + k0 + tx] = f32_bf16(tile[tx][ty + i * 8]);
}

// ---------------- LayerNorm (fp32 in -> bf16 out), one block per row ----------------
__global__ __launch_bounds__(256) void ln_bf16(const float* __restrict__ x,
                                               const float* __restrict__ w,
                                               const float* __restrict__ bb,
                                               unsigned short* __restrict__ out) {
    int row = blockIdx.x;
    int tid = threadIdx.x;
    float4 v = ((const float4*)(x + (size_t)row * H_DIM))[tid];
    float s  = v.x + v.y + v.z + v.w;
    float s2 = v.x*v.x + v.y*v.y + v.z*v.z + v.w*v.w;
    #pragma unroll
    for (int off = 1; off < 64; off <<= 1) {
        s  += __shfl_xor(s,  off, 64);
        s2 += __shfl_xor(s2, off, 64);
    }
    __shared__ float red[8];
    int wv = tid >> 6;
    if ((tid & 63) == 0) { red[wv] = s; red[4 + wv] = s2; }
    __syncthreads();
    s  = red[0] + red[1] + red[2] + red[3];
    s2 = red[4] + red[5] + red[6] + red[7];
    float mu = s * (1.0f / H_DIM);
    float rs = rsqrtf(s2 * (1.0f / H_DIM) - mu * mu + 1e-5f);
    float4 wv4 = ((const float4*)w)[tid];
    float4 bv4 = ((const float4*)bb)[tid];
    ushort4 o;
    o.x = f32_bf16((v.x - mu) * rs * wv4.x + bv4.x);
    o.y = f32_bf16((v.y - mu) * rs * wv4.y + bv4.y);
    o.z = f32_bf16((v.z - mu) * rs * wv4.z + bv4.z);
    o.w = f32_bf16((v.w - mu) * rs * wv4.w + bv4.w);
    ((ushort4*)(out + (size_t)row * H_DIM))[tid] = o;
}

// ---------------- bf16 MFMA GEMM, 128x128 tile, BK=64, swizzled LDS ----------------
template<int EPI>
__global__ __launch_bounds__(256) void gemm128(const unsigned short* __restrict__ A,
                                               const unsigned short* __restrict__ Bt,
                                               const float* __restrict__ bias,
                                               const float* __restrict__ resid,
                                               float* __restrict__ outF,
                                               unsigned short* __restrict__ outH,
                                               unsigned short* __restrict__ outH2,
                                               int N, int K) {
    __shared__ __attribute__((aligned(16))) unsigned short As[128][64];
    __shared__ __attribute__((aligned(16))) unsigned short Bs[128][64];
    int tid = threadIdx.x;
    int w = tid >> 6, l = tid & 63;
    int l15 = l & 15, lg = l >> 4;
    int wm = w & 1, wn = w >> 1;
    int m0 = blockIdx.y * 128, n0 = blockIdx.x * 128;

    f32x4 acc[4][4] = {};

    const unsigned short* aptr[4];
    const unsigned short* bptr[4];
    unsigned short* lA[4];
    unsigned short* lB[4];
    #pragma unroll
    for (int j = 0; j < 4; ++j) {
        int slot = (w * 4 + j) * 64 + l;          // 0..1023
        int row = slot >> 3;
        int lchunk = (slot & 7) ^ (row & 7);      // source chunk for this physical slot
        aptr[j] = A  + (size_t)(m0 + row) * K + lchunk * 8;
        bptr[j] = Bt + (size_t)(n0 + row) * K + lchunk * 8;
        lA[j] = &As[0][0] + (w * 4 + j) * 512;
        lB[j] = &Bs[0][0] + (w * 4 + j) * 512;
    }
    int swz[2];
    swz[0] = ((0 + lg) ^ (l15 & 7)) * 8;
    swz[1] = ((4 + lg) ^ (l15 & 7)) * 8;
    const unsigned short* pA = &As[wm * 64 + l15][0];
    const unsigned short* pB = &Bs[wn * 64 + l15][0];

    for (int k0 = 0; k0 < K; k0 += 64) {
        __syncthreads();
        #pragma unroll
        for (int j = 0; j < 4; ++j) gload16(aptr[j] + k0, lA[j]);
        #pragma unroll
        for (int j = 0; j < 4; ++j) gload16(bptr[j] + k0, lB[j]);
        __syncthreads();

        #pragma unroll
        for (int ks = 0; ks < 2; ++ks) {
            short8 af[4], bf[4];
            #pragma unroll
            for (int mi = 0; mi < 4; ++mi)
                af[mi] = *(const short8*)(pA + mi * 16 * 64 + swz[ks]);
            #pragma unroll
            for (int ni = 0; ni < 4; ++ni)
                bf[ni] = *(const short8*)(pB + ni * 16 * 64 + swz[ks]);
            #pragma unroll
            for (int mi = 0; mi < 4; ++mi)
                #pragma unroll
                for (int ni = 0; ni < 4; ++ni)
                    acc[mi][ni] = __builtin_amdgcn_mfma_f32_16x16x32_bf16(af[mi], bf[ni], acc[mi][ni], 0, 0, 0);
        }
    }

    #pragma unroll
    for (int mi = 0; mi < 4; ++mi) {
        #pragma unroll
        for (int ni = 0; ni < 4; ++ni) {
            int col = n0 + wn * 64 + ni * 16 + l15;
            float bv = bias[col];
            if (EPI == 4 && col >= 2048) {
                int row0 = m0 + wm * 64 + mi * 16 + lg * 4;
                int bb = row0 >> 11, ss = row0 & 2047;
                int hd = col - 2048;
                ushort4 u;
                u.x = f32_bf16(acc[mi][ni][0] + bv);
                u.y = f32_bf16(acc[mi][ni][1] + bv);
                u.z = f32_bf16(acc[mi][ni][2] + bv);
                u.w = f32_bf16(acc[mi][ni][3] + bv);
                *(ushort4*)&outH2[((size_t)bb * 1024 + hd) * SEQ + ss] = u;
            } else {
                #pragma unroll
                for (int j = 0; j < 4; ++j) {
                    int row = m0 + wm * 64 + mi * 16 + lg * 4 + j;
                    size_t idx = (size_t)row * N + col;
                    float c = acc[mi][ni][j] + bv;
                    if (EPI == 0) {
                        outF[idx] = c;
                    } else if (EPI == 1) {
                        outF[idx] = resid[idx] + c;
                    } else if (EPI == 2) {
                        float g = 0.5f * c * (1.0f + fast_erf(c * 0.70710678118f));
                        outH[idx] = f32_bf16(g);
                    } else if (EPI == 3) {
                        outH[idx] = f32_bf16(c);
                    } else {
                        outH[(size_t)row * 2048 + col] = f32_bf16(c);   // Q|K packed
                    }
                }
            }
        }
    }
}

// ---------------- causal flash attention, swapped-operand softmax ----------------
// qk: bf16 [ROWS][2048] (Q | K); vT: bf16 [B*NH*DKV][SEQ] (V transposed).
// QK^T computed as mfma(K,Q): lane holds S[k=st*16+lg*4+j][q=l15] -> per-lane
// q-row softmax (2 shfl stages). PV computed as mfma(V,P): O[d=lg*4+j][q=l15],
// so rescale/normalize are lane-local and output stores are ushort4.
__global__ __launch_bounds__(256) void attn_mfma(const unsigned short* __restrict__ qk,
                                                 const unsigned short* __restrict__ vT,
                                                 unsigned short* __restrict__ out) {
    int bid = blockIdx.x;
    int swz = (bid & 7) * 128 + (bid >> 3);   // 1024 % 8 == 0 -> bijective
    int b  = swz >> 9;
    int h  = (swz >> 5) & 15;
    int qt = 31 - (swz & 31);                 // long blocks first within group
    int tid = threadIdx.x;
    int w = tid >> 6, l = tid & 63;
    int l15 = l & 15, lg = l >> 4;

    __shared__ __attribute__((aligned(16))) unsigned short Ks[64][72];
    __shared__ __attribute__((aligned(16))) unsigned short Vt[64][72];  // Vt[d][k]
    __shared__ __attribute__((aligned(16))) unsigned short Ps[4][16][72];

    int qrow = qt * 64 + w * 16 + l15;        // this lane's q row
    // Q fragment (B-operand): lane holds Q[q=l15][d = dstep*32 + lg*8 + 0..7]
    short8 qf[2];
    {
        const unsigned short* qp = qk + (size_t)(b * SEQ + qrow) * 2048 + h * DKV + lg * 8;
        qf[0] = *(const short8*)qp;
        qf[1] = *(const short8*)(qp + 32);
    }

    int srow = l >> 2;
    int scol = (l & 3) * 16;
    int krow = w * 16 + srow;
    const unsigned short* kbase = qk + (size_t)(b * SEQ + krow) * 2048 + 1024 + h * DKV + scol;
    const unsigned short* vbase = vT + ((size_t)(b * NHEAD + h) * DKV + krow) * SEQ + scol;

    // prefetch tile 0 into registers (T14 async-stage split)
    short8 kr0 = *(const short8*)kbase;
    short8 kr1 = *(const short8*)(kbase + 8);
    short8 vr0 = *(const short8*)vbase;
    short8 vr1 = *(const short8*)(vbase + 8);

    float m = -1e30f, lsum = 0.0f;
    f32x4 oacc[4] = {};   // oacc[dblk][j] = O[q=l15][d = dblk*16 + lg*4 + j]

    for (int kt = 0; kt <= qt; ++kt) {
        __syncthreads();   // previous tile's LDS reads complete
        *(short8*)&Ks[krow][scol]     = kr0;
        *(short8*)&Ks[krow][scol + 8] = kr1;
        *(short8*)&Vt[krow][scol]     = vr0;
        *(short8*)&Vt[krow][scol + 8] = vr1;
        __syncthreads();   // staged tile visible
        if (kt < qt) {     // issue next-tile loads; land during compute below
            const unsigned short* kp = kbase + (size_t)(kt + 1) * 64 * 2048;
            const unsigned short* vp = vbase + (kt + 1) * 64;
            kr0 = *(const short8*)kp;
            kr1 = *(const short8*)(kp + 8);
            vr0 = *(const short8*)vp;
            vr1 = *(const short8*)(vp + 8);
        }

        // QK^T swapped: sc[st] holds S[k = kt*64 + st*16 + lg*4 + j][q = l15]
        f32x4 sc[4] = {};
        __builtin_amdgcn_s_setprio(1);
        #pragma unroll
        for (int dstep = 0; dstep < 2; ++dstep) {
            #pragma unroll
            for (int st = 0; st < 4; ++st) {
                short8 kf = *(const short8*)&Ks[st * 16 + l15][dstep * 32 + lg * 8];
                sc[st] = __builtin_amdgcn_mfma_f32_16x16x32_bf16(kf, qf[dstep], sc[st], 0, 0, 0);
            }
        }
        __builtin_amdgcn_s_setprio(0);

        // per-lane softmax over 16 k-values; cross-lg reduce (2 stages)
        bool diag = (kt == qt);
        int klim = w * 16 + l15;              // within-tile q position (diag only)
        float pv[4][4];
        float pmax = -1e30f;
        #pragma unroll
        for (int st = 0; st < 4; ++st) {
            #pragma unroll
            for (int j = 0; j < 4; ++j) {
                float s = sc[st][j] * 0.125f;
                if (diag && (st * 16 + lg * 4 + j > klim)) s = -1e30f;
                pv[st][j] = s;
                pmax = fmaxf(pmax, s);
            }
        }
        pmax = fmaxf(pmax, __shfl_xor(pmax, 16, 64));
        pmax = fmaxf(pmax, __shfl_xor(pmax, 32, 64));

        // defer-max (T13): skip rescale when growth small; P bounded by e^8
        if (!__all(pmax - m <= 8.0f)) {
            float mn = fmaxf(m, pmax);
            float scl = __expf(m - mn);
            lsum *= scl;
            #pragma unroll
            for (int d = 0; d < 4; ++d)
                #pragma unroll
                for (int j = 0; j < 4; ++j)
                    oacc[d][j] *= scl;
            m = mn;
        }

        float ps = 0.0f;
        #pragma unroll
        for (int st = 0; st < 4; ++st) {
            ushort4 u;
            #pragma unroll
            for (int j = 0; j < 4; ++j) {
                float p = __expf(pv[st][j] - m);
                ps += p;
                ((unsigned short*)&u)[j] = f32_bf16(p);
            }
            *(ushort4*)&Ps[w][l15][st * 16 + lg * 4] = u;   // j-contiguous in k
        }
        ps += __shfl_xor(ps, 16, 64);
        ps += __shfl_xor(ps, 32, 64);
        lsum += ps;

        // PV: mfma(V, P) -> O[d = lg*4+j][q = l15]
        __builtin_amdgcn_s_setprio(1);
        #pragma unroll
        for (int ks = 0; ks < 2; ++ks) {
            short8 pf = *(const short8*)&Ps[w][l15][ks * 32 + lg * 8];
            #pragma unroll
            for (int d = 0; d < 4; ++d) {
                short8 vf = *(const short8*)&Vt[d * 16 + l15][ks * 32 + lg * 8];
                oacc[d] = __builtin_amdgcn_mfma_f32_16x16x32_bf16(vf, pf, oacc[d], 0, 0, 0);
            }
        }
        __builtin_amdgcn_s_setprio(0);
    }

    float inv = 1.0f / lsum;
    size_t ob = (size_t)(b * SEQ + qrow) * H_DIM + h * DKV;
    #pragma unroll
    for (int d = 0; d < 4; ++d) {
        ushort4 u;
        #pragma unroll
        for (int j = 0; j < 4; ++j)
            ((unsigned short*)&u)[j] = f32_bf16(oacc[d][j] * inv);
        *(ushort4*)&out[ob + d * 16 + lg * 4] = u;
    }
}

// ---------------- launch ----------------
extern "C" void kernel_launch(void* const* d_in, const int* in_sizes, int n_in,
                              void* d_out, int out_size, void* d_ws, size_t ws_size,
                              hipStream_t stream) {
    const float* x     = (const float*)d_in[0];
    const float* ln1w  = (const float*)d_in[1];
    const float* ln1b  = (const float*)d_in[2];
    const float* Wqkv  = (const float*)d_in[3];
    const float* bqkv  = (const float*)d_in[4];
    const float* Wo    = (const float*)d_in[5];
    const float* bo    = (const float*)d_in[6];
    const float* ln2w  = (const float*)d_in[7];
    const float* ln2b  = (const float*)d_in[8];
    const float* Wfc   = (const float*)d_in[9];
    const float* bfc   = (const float*)d_in[10];
    const float* Wproj = (const float*)d_in[11];
    const float* bproj = (const float*)d_in[12];
    float* out = (float*)d_out;

    char* ws = (char*)d_ws;
    size_t off = 0;
    auto take = [&](size_t bytes) {
        void* p = ws + off;
        off += (bytes + 255) & ~(size_t)255;
        return p;
    };

    unsigned short* WqT  = (unsigned short*)take((size_t)3072 * 1024 * 2);
    unsigned short* WoT  = (unsigned short*)take((size_t)1024 * 1024 * 2);
    unsigned short* WfcT = (unsigned short*)take((size_t)4096 * 1024 * 2);
    unsigned short* WpT  = (unsigned short*)take((size_t)1024 * 4096 * 2);
    unsigned short* xn1   = (unsigned short*)take((size_t)ROWS * 1024 * 2);
    unsigned short* qk_h  = (unsigned short*)take((size_t)ROWS * 2048 * 2);
    unsigned short* vT    = (unsigned short*)take((size_t)ROWS * 1024 * 2);   // [B*NH*DKV][SEQ]
    unsigned short* attn  = (unsigned short*)take((size_t)ROWS * 1024 * 2);
    float*          x1    = (float*)take((size_t)ROWS * 1024 * 4);
    unsigned short* xn2   = (unsigned short*)take((size_t)ROWS * 1024 * 2);
    unsigned short* hbuf  = (unsigned short*)take((size_t)ROWS * 4096 * 2);

    // weight transposes fp32[K][N] -> bf16[N][K]
    transpose_bf16<<<dim3(3072 / 32, 1024 / 32), 256, 0, stream>>>(Wqkv,  WqT,  1024, 3072);
    transpose_bf16<<<dim3(1024 / 32, 1024 / 32), 256, 0, stream>>>(Wo,    WoT,  1024, 1024);
    transpose_bf16<<<dim3(4096 / 32, 1024 / 32), 256, 0, stream>>>(Wfc,   WfcT, 1024, 4096);
    transpose_bf16<<<dim3(1024 / 32, 4096 / 32), 256, 0, stream>>>(Wproj, WpT,  4096, 1024);

    // LN1 -> xn1 (bf16)
    ln_bf16<<<ROWS, 256, 0, stream>>>(x, ln1w, ln1b, xn1);

    // QKV: Q|K -> qk_h packed, V -> vT transposed
    gemm128<4><<<dim3(3072 / 128, ROWS / 128), 256, 0, stream>>>(xn1, WqT, bqkv, nullptr, nullptr, qk_h, vT, 3072, 1024);

    // causal attention -> attn (bf16)
    attn_mfma<<<1024, 256, 0, stream>>>(qk_h, vT, attn);

    // x1 = x + attn @ Wo + bo
    gemm128<1><<<dim3(1024 / 128, ROWS / 128), 256, 0, stream>>>(attn, WoT, bo, x, x1, nullptr, nullptr, 1024, 1024);

    // LN2 -> xn2 (bf16)
    ln_bf16<<<ROWS, 256, 0, stream>>>(x1, ln2w, ln2b, xn2);

    // h = gelu(xn2 @ Wfc + bfc) (bf16)
    gemm128<2><<<dim3(4096 / 128, ROWS / 128), 256, 0, stream>>>(xn2, WfcT, bfc, nullptr, nullptr, hbuf, nullptr, 4096, 1024);

    // out = x1 + h @ Wproj + bproj
    gemm128<1><<<dim3(1024 / 128, ROWS / 128), 256, 0, stream>>>(hbuf, WpT, bproj, x1, out, nullptr, nullptr, 1024, 4096);
}